// Round 2
// baseline (4220.558 us; speedup 1.0000x reference)
//
#include <hip/hip_runtime.h>
#include <hip/hip_bf16.h>

typedef __hip_bfloat16 bf16;
typedef __attribute__((ext_vector_type(8))) short short8;   // 8 bf16 (4 VGPRs)
typedef __attribute__((ext_vector_type(4))) float f32x4;

#define NB 2
#define NT 2048
#define ND 2048
#define NH 32
#define NM (NB*NT)   // 4096 rows

// ---- dtype hedge: inputs may be bf16 (harness-converted) or fp32 (per reference) ----
// Even halfword positions of a bf16 buffer are N(0,1)-scale samples (exp field <= ~130).
// For an fp32 buffer they are low mantissa bits (uniform -> ~45% have exp >= 141).
__global__ void detect_dtype(const unsigned short* __restrict__ hs, int* __restrict__ flag) {
  if (threadIdx.x == 0 && blockIdx.x == 0) {
    int cnt = 0;
    for (int i = 0; i < 2048; i += 2) {
      int e = (hs[i] >> 7) & 0xFF;
      if (e >= 141) ++cnt;
    }
    *flag = (cnt > 64) ? 1 : 0;   // 1 = fp32, 0 = bf16
  }
}

__device__ __forceinline__ float loadf(const void* p, size_t i, int isf32) {
  return isf32 ? ((const float*)p)[i] : __bfloat162float(((const bf16*)p)[i]);
}

// ---- normalize an input array to bf16 in ws (copy if already bf16) ----
__global__ __launch_bounds__(256) void convert_bf16(const void* __restrict__ src,
                                                    bf16* __restrict__ dst,
                                                    long n, const int* __restrict__ flag) {
  const long i0 = ((long)blockIdx.x * 256 + threadIdx.x) * 8;
  if (i0 >= n) return;
  if (*flag) {
    const float* s = (const float*)src;
    #pragma unroll
    for (int j = 0; j < 8; ++j) dst[i0 + j] = __float2bfloat16(s[i0 + j]);
  } else {
    *(short8*)(dst + i0) = *(const short8*)((const bf16*)src + i0);
  }
}

// ---- transpose + convert: dst[c][r] = bf16(src[r][c]) ----
__global__ __launch_bounds__(256) void transpose_cvt(const void* __restrict__ src,
                                                     bf16* __restrict__ dst,
                                                     int rows, int cols,
                                                     const int* __restrict__ flag) {
  __shared__ bf16 tile[64][65];
  const int f = *flag;
  const int tb_r = blockIdx.y * 64, tb_c = blockIdx.x * 64;
  const int tx = threadIdx.x & 63, ty = threadIdx.x >> 6;
  #pragma unroll
  for (int i = 0; i < 64; i += 4)
    tile[i + ty][tx] = __float2bfloat16(loadf(src, (size_t)(tb_r + i + ty) * cols + tb_c + tx, f));
  __syncthreads();
  #pragma unroll
  for (int i = 0; i < 64; i += 4)
    dst[(size_t)(tb_c + i + ty) * rows + tb_r + tx] = tile[tx][i + ty];
}

// async 16B/lane global->LDS (wave-uniform LDS base + lane*16)
__device__ __forceinline__ void gload_lds16(const void* g, void* l) {
  __builtin_amdgcn_global_load_lds((__attribute__((address_space(1))) const void*)g,
                                   (__attribute__((address_space(3))) void*)l,
                                   16, 0, 0);
}

// ------------- GEMM: C[M][N] = A[M][K] @ Bt[N][K]^T  (bf16 in, fp32 acc) -------------
// If outflag == nullptr: write bf16 to Cb. Else: write to outv as fp32/bf16 per *outflag.
__global__ __launch_bounds__(256) void gemm_bt(const bf16* __restrict__ A,
                                               const bf16* __restrict__ Bt,
                                               bf16* __restrict__ Cb,
                                               void* __restrict__ outv,
                                               const int* __restrict__ outflag,
                                               int M, int N, int K) {
  __shared__ bf16 As[128 * 32];
  __shared__ bf16 Bs[128 * 32];
  const int tid = threadIdx.x;
  const int wave = tid >> 6, lane = tid & 63;
  const int m0 = blockIdx.y * 128, n0 = blockIdx.x * 128;
  const int wm = (wave >> 1) * 64, wn = (wave & 1) * 64;
  const int srow = lane >> 2, scol = (lane & 3) * 8;   // staging: 16 rows x 4 chunks of 8 bf16
  const int frow = lane & 15, fk = (lane >> 4) * 8;    // fragment: [m=lane&15][k=quad*8+j]
  f32x4 acc[4][4] = {};

  for (int kb = 0; kb < K; kb += 32) {
    __syncthreads();   // previous iter's LDS reads done before overwrite
    #pragma unroll
    for (int j = 0; j < 2; ++j) {
      const int rbase = wave * 32 + j * 16;
      gload_lds16(A  + (size_t)(m0 + rbase + srow) * K + kb + scol, As + rbase * 32);
      gload_lds16(Bt + (size_t)(n0 + rbase + srow) * K + kb + scol, Bs + rbase * 32);
    }
    __syncthreads();   // barrier drains vmcnt -> staged data visible
    short8 af[4], bfr[4];
    #pragma unroll
    for (int i = 0; i < 4; ++i)
      af[i] = *(const short8*)(As + (wm + i * 16 + frow) * 32 + fk);
    #pragma unroll
    for (int i = 0; i < 4; ++i)
      bfr[i] = *(const short8*)(Bs + (wn + i * 16 + frow) * 32 + fk);
    #pragma unroll
    for (int mi = 0; mi < 4; ++mi)
      #pragma unroll
      for (int ni = 0; ni < 4; ++ni)
        acc[mi][ni] = __builtin_amdgcn_mfma_f32_16x16x32_bf16(af[mi], bfr[ni], acc[mi][ni], 0, 0, 0);
  }

  // C/D layout: col = lane&15, row = (lane>>4)*4 + reg  [m89-verified]
  const int crow = (lane >> 4) * 4, ccol = lane & 15;
  const int f = outflag ? *outflag : -1;
  #pragma unroll
  for (int mi = 0; mi < 4; ++mi)
    #pragma unroll
    for (int ni = 0; ni < 4; ++ni)
      #pragma unroll
      for (int r = 0; r < 4; ++r) {
        const size_t idx = (size_t)(m0 + wm + mi * 16 + crow + r) * N + (n0 + wn + ni * 16 + ccol);
        const float val = acc[mi][ni][r];
        if (f < 0)       Cb[idx] = __float2bfloat16(val);
        else if (f == 1) ((float*)outv)[idx] = val;
        else             ((bf16*)outv)[idx] = __float2bfloat16(val);
      }
}

// ---------------- beta = sigmoid(hs @ Wb + bb): [4096][32] fp32 ----------------
__global__ __launch_bounds__(256) void beta_kernel(const bf16* __restrict__ hs,
                                                   const bf16* __restrict__ Wb,
                                                   const void* __restrict__ bb,
                                                   float* __restrict__ beta,
                                                   const int* __restrict__ flag) {
  const int row = blockIdx.x * 8 + (threadIdx.x >> 5);
  const int col = threadIdx.x & 31;
  const bf16* hrow = hs + (size_t)row * ND;
  float sum = 0.f;
  for (int k = 0; k < ND; ++k)
    sum += __bfloat162float(hrow[k]) * __bfloat162float(Wb[(size_t)k * NH + col]);
  sum += loadf(bb, col, *flag);
  beta[(size_t)row * NH + col] = 1.f / (1.f + expf(-sum));
}

// ---------------- in-place L2 norm over each 64-elem head segment (bf16) ----------------
__global__ __launch_bounds__(256) void l2norm_bf16(bf16* __restrict__ x) {
  const size_t rh = (size_t)blockIdx.x * 4 + (threadIdx.x >> 6);  // row-head index
  const int lane = threadIdx.x & 63;
  const float v = __bfloat162float(x[rh * 64 + lane]);
  float s = v * v;
  #pragma unroll
  for (int m = 32; m >= 1; m >>= 1) s += __shfl_xor(s, m, 64);
  x[rh * 64 + lane] = __float2bfloat16(v / sqrtf(s + 1e-6f));
}

// ---------------- sequential delta-rule scan ----------------
// One wave per (b,h); lane = v-column; S column (64 fp32) in VGPRs.
// q/k rows broadcast via wave-uniform uint4 loads; bf16 -> fp32 unpack is a shift.
// o is written IN PLACE over v (v[row] is read before o[row] is written, same wave).
__global__ __launch_bounds__(64) void scan_kernel(const bf16* __restrict__ qn,
                                                  const bf16* __restrict__ kn,
                                                  bf16* __restrict__ vo,
                                                  const float* __restrict__ beta) {
  const int b = blockIdx.x >> 5, h = blockIdx.x & 31;
  const int lane = threadIdx.x;
  float S[64];
  #pragma unroll
  for (int i = 0; i < 64; ++i) S[i] = 0.f;
  const size_t base = (size_t)b * NT * ND + (size_t)h * 64;
  for (int t = 0; t < NT; ++t) {
    const size_t row = base + (size_t)t * ND;
    const uint4* kp = (const uint4*)(kn + row);   // wave-uniform -> broadcast
    const uint4* qp = (const uint4*)(qn + row);
    const float v_c = __bfloat162float(vo[row + lane]);
    const float b_t = beta[((size_t)b * NT + t) * NH + h];
    float kv[64], qv[64];
    #pragma unroll
    for (int i = 0; i < 8; ++i) {
      const uint4 ku = kp[i], qu = qp[i];
      kv[8*i+0] = __uint_as_float(ku.x << 16); kv[8*i+1] = __uint_as_float(ku.x & 0xffff0000u);
      kv[8*i+2] = __uint_as_float(ku.y << 16); kv[8*i+3] = __uint_as_float(ku.y & 0xffff0000u);
      kv[8*i+4] = __uint_as_float(ku.z << 16); kv[8*i+5] = __uint_as_float(ku.z & 0xffff0000u);
      kv[8*i+6] = __uint_as_float(ku.w << 16); kv[8*i+7] = __uint_as_float(ku.w & 0xffff0000u);
      qv[8*i+0] = __uint_as_float(qu.x << 16); qv[8*i+1] = __uint_as_float(qu.x & 0xffff0000u);
      qv[8*i+2] = __uint_as_float(qu.y << 16); qv[8*i+3] = __uint_as_float(qu.y & 0xffff0000u);
      qv[8*i+4] = __uint_as_float(qu.z << 16); qv[8*i+5] = __uint_as_float(qu.z & 0xffff0000u);
      qv[8*i+6] = __uint_as_float(qu.w << 16); qv[8*i+7] = __uint_as_float(qu.w & 0xffff0000u);
    }
    float p0 = 0, p1 = 0, p2 = 0, p3 = 0;
    #pragma unroll
    for (int i = 0; i < 16; ++i) {
      p0 += kv[4*i+0] * S[4*i+0];
      p1 += kv[4*i+1] * S[4*i+1];
      p2 += kv[4*i+2] * S[4*i+2];
      p3 += kv[4*i+3] * S[4*i+3];
    }
    const float delta = (v_c - ((p0 + p1) + (p2 + p3))) * b_t;
    float o0 = 0, o1 = 0, o2 = 0, o3 = 0;
    #pragma unroll
    for (int i = 0; i < 16; ++i) {
      S[4*i+0] += kv[4*i+0] * delta; o0 += qv[4*i+0] * S[4*i+0];
      S[4*i+1] += kv[4*i+1] * delta; o1 += qv[4*i+1] * S[4*i+1];
      S[4*i+2] += kv[4*i+2] * delta; o2 += qv[4*i+2] * S[4*i+2];
      S[4*i+3] += kv[4*i+3] * delta; o3 += qv[4*i+3] * S[4*i+3];
    }
    vo[row + lane] = __float2bfloat16((o0 + o1) + (o2 + o3));
  }
}

extern "C" void kernel_launch(void* const* d_in, const int* in_sizes, int n_in,
                              void* d_out, int out_size, void* d_ws, size_t ws_size,
                              hipStream_t stream) {
  const void* hs = d_in[0];
  const void* Wq = d_in[1];
  const void* Wk = d_in[2];
  const void* Wv = d_in[3];
  const void* Wb = d_in[4];
  const void* bb = d_in[5];
  const void* Wo = d_in[6];

  char* ws = (char*)d_ws;
  size_t off = 0;
  auto alloc = [&](size_t bytes) {
    void* p = ws + off;
    off += (bytes + 255) & ~(size_t)255;
    return p;
  };
  int*   flag   = (int*)  alloc(256);
  bf16*  Wt     = (bf16*) alloc((size_t)ND * ND * 2);    // 8 MB, reused x4
  bf16*  hs16   = (bf16*) alloc((size_t)NM * ND * 2);    // 16 MB
  bf16*  q16    = (bf16*) alloc((size_t)NM * ND * 2);    // 16 MB
  bf16*  k16    = (bf16*) alloc((size_t)NM * ND * 2);    // 16 MB
  bf16*  v16    = (bf16*) alloc((size_t)NM * ND * 2);    // 16 MB (o written in place)
  bf16*  Wb16   = (bf16*) alloc((size_t)ND * NH * 2);    // 128 KB
  float* betaws = (float*)alloc((size_t)NM * NH * 4);    // 512 KB
  // total ~73 MB

  const dim3 tgrid(ND / 64, ND / 64);
  const dim3 ggrid(ND / 128, NM / 128);

  detect_dtype<<<1, 64, 0, stream>>>((const unsigned short*)hs, flag);
  convert_bf16<<<(NM * ND) / (256 * 8), 256, 0, stream>>>(hs, hs16, (long)NM * ND, flag);

  transpose_cvt<<<tgrid, 256, 0, stream>>>(Wq, Wt, ND, ND, flag);
  gemm_bt<<<ggrid, 256, 0, stream>>>(hs16, Wt, q16, nullptr, nullptr, NM, ND, ND);
  transpose_cvt<<<tgrid, 256, 0, stream>>>(Wk, Wt, ND, ND, flag);
  gemm_bt<<<ggrid, 256, 0, stream>>>(hs16, Wt, k16, nullptr, nullptr, NM, ND, ND);
  transpose_cvt<<<tgrid, 256, 0, stream>>>(Wv, Wt, ND, ND, flag);
  gemm_bt<<<ggrid, 256, 0, stream>>>(hs16, Wt, v16, nullptr, nullptr, NM, ND, ND);

  convert_bf16<<<(ND * NH) / (256 * 8), 256, 0, stream>>>(Wb, Wb16, (long)ND * NH, flag);
  beta_kernel<<<NM / 8, 256, 0, stream>>>(hs16, Wb16, bb, betaws, flag);
  l2norm_bf16<<<NM * NH / 4, 256, 0, stream>>>(q16);
  l2norm_bf16<<<NM * NH / 4, 256, 0, stream>>>(k16);

  scan_kernel<<<NB * NH, 64, 0, stream>>>(q16, k16, v16, betaws);

  transpose_cvt<<<tgrid, 256, 0, stream>>>(Wo, Wt, ND, ND, flag);
  gemm_bt<<<ggrid, 256, 0, stream>>>(v16, Wt, nullptr, d_out, flag, NM, ND, ND);
}

// Round 3
// 870.157 us; speedup vs baseline: 4.8503x; 4.8503x over previous
//
#include <hip/hip_runtime.h>
#include <hip/hip_bf16.h>

typedef __hip_bfloat16 bf16;
typedef __attribute__((ext_vector_type(8))) short short8;   // 8 bf16 (4 VGPRs)
typedef __attribute__((ext_vector_type(4))) float f32x4;

#define NB 2
#define NT 2048
#define ND 2048
#define NH 32
#define NM (NB*NT)   // 4096 rows
#define NCH 32       // chunks per (b,h): NT/64

// ---- dtype hedge: inputs may be bf16 (harness-converted) or fp32 (per reference) ----
__global__ void detect_dtype(const unsigned short* __restrict__ hs, int* __restrict__ flag) {
  if (threadIdx.x == 0 && blockIdx.x == 0) {
    int cnt = 0;
    for (int i = 0; i < 2048; i += 2) {
      int e = (hs[i] >> 7) & 0xFF;
      if (e >= 141) ++cnt;
    }
    *flag = (cnt > 64) ? 1 : 0;   // 1 = fp32, 0 = bf16
  }
}

__device__ __forceinline__ float loadf(const void* p, size_t i, int isf32) {
  return isf32 ? ((const float*)p)[i] : __bfloat162float(((const bf16*)p)[i]);
}

__global__ __launch_bounds__(256) void convert_bf16(const void* __restrict__ src,
                                                    bf16* __restrict__ dst,
                                                    long n, const int* __restrict__ flag) {
  const long i0 = ((long)blockIdx.x * 256 + threadIdx.x) * 8;
  if (i0 >= n) return;
  if (*flag) {
    const float* s = (const float*)src;
    #pragma unroll
    for (int j = 0; j < 8; ++j) dst[i0 + j] = __float2bfloat16(s[i0 + j]);
  } else {
    *(short8*)(dst + i0) = *(const short8*)((const bf16*)src + i0);
  }
}

// ---- transpose + convert: dst[c][r] = bf16(src[r][c]) ----
__global__ __launch_bounds__(256) void transpose_cvt(const void* __restrict__ src,
                                                     bf16* __restrict__ dst,
                                                     int rows, int cols,
                                                     const int* __restrict__ flag) {
  __shared__ bf16 tile[64][65];
  const int f = *flag;
  const int tb_r = blockIdx.y * 64, tb_c = blockIdx.x * 64;
  const int tx = threadIdx.x & 63, ty = threadIdx.x >> 6;
  #pragma unroll
  for (int i = 0; i < 64; i += 4)
    tile[i + ty][tx] = __float2bfloat16(loadf(src, (size_t)(tb_r + i + ty) * cols + tb_c + tx, f));
  __syncthreads();
  #pragma unroll
  for (int i = 0; i < 64; i += 4)
    dst[(size_t)(tb_c + i + ty) * rows + tb_r + tx] = tile[tx][i + ty];
}

// async 16B/lane global->LDS (wave-uniform LDS base + lane*16)
__device__ __forceinline__ void gload_lds16(const void* g, void* l) {
  __builtin_amdgcn_global_load_lds((__attribute__((address_space(1))) const void*)g,
                                   (__attribute__((address_space(3))) void*)l,
                                   16, 0, 0);
}

// ------------- GEMM: C[M][N] = A[M][K] @ Bt[N][K]^T  (bf16 in, fp32 acc) -------------
__global__ __launch_bounds__(256) void gemm_bt(const bf16* __restrict__ A,
                                               const bf16* __restrict__ Bt,
                                               bf16* __restrict__ Cb,
                                               void* __restrict__ outv,
                                               const int* __restrict__ outflag,
                                               int M, int N, int K) {
  __shared__ bf16 As[128 * 32];
  __shared__ bf16 Bs[128 * 32];
  const int tid = threadIdx.x;
  const int wave = tid >> 6, lane = tid & 63;
  const int m0 = blockIdx.y * 128, n0 = blockIdx.x * 128;
  const int wm = (wave >> 1) * 64, wn = (wave & 1) * 64;
  const int srow = lane >> 2, scol = (lane & 3) * 8;
  const int frow = lane & 15, fk = (lane >> 4) * 8;
  f32x4 acc[4][4] = {};

  for (int kb = 0; kb < K; kb += 32) {
    __syncthreads();
    #pragma unroll
    for (int j = 0; j < 2; ++j) {
      const int rbase = wave * 32 + j * 16;
      gload_lds16(A  + (size_t)(m0 + rbase + srow) * K + kb + scol, As + rbase * 32);
      gload_lds16(Bt + (size_t)(n0 + rbase + srow) * K + kb + scol, Bs + rbase * 32);
    }
    __syncthreads();
    short8 af[4], bfr[4];
    #pragma unroll
    for (int i = 0; i < 4; ++i)
      af[i] = *(const short8*)(As + (wm + i * 16 + frow) * 32 + fk);
    #pragma unroll
    for (int i = 0; i < 4; ++i)
      bfr[i] = *(const short8*)(Bs + (wn + i * 16 + frow) * 32 + fk);
    #pragma unroll
    for (int mi = 0; mi < 4; ++mi)
      #pragma unroll
      for (int ni = 0; ni < 4; ++ni)
        acc[mi][ni] = __builtin_amdgcn_mfma_f32_16x16x32_bf16(af[mi], bfr[ni], acc[mi][ni], 0, 0, 0);
  }

  const int crow = (lane >> 4) * 4, ccol = lane & 15;
  const int f = outflag ? *outflag : -1;
  #pragma unroll
  for (int mi = 0; mi < 4; ++mi)
    #pragma unroll
    for (int ni = 0; ni < 4; ++ni)
      #pragma unroll
      for (int r = 0; r < 4; ++r) {
        const size_t idx = (size_t)(m0 + wm + mi * 16 + crow + r) * N + (n0 + wn + ni * 16 + ccol);
        const float val = acc[mi][ni][r];
        if (f < 0)       Cb[idx] = __float2bfloat16(val);
        else if (f == 1) ((float*)outv)[idx] = val;
        else             ((bf16*)outv)[idx] = __float2bfloat16(val);
      }
}

// ---------------- beta = sigmoid(hs @ Wb + bb): [4096][32] fp32 ----------------
__global__ __launch_bounds__(256) void beta_kernel(const bf16* __restrict__ hs,
                                                   const bf16* __restrict__ Wb,
                                                   const void* __restrict__ bb,
                                                   float* __restrict__ beta,
                                                   const int* __restrict__ flag) {
  const int row = blockIdx.x * 8 + (threadIdx.x >> 5);
  const int col = threadIdx.x & 31;
  const bf16* hrow = hs + (size_t)row * ND;
  float sum = 0.f;
  for (int k = 0; k < ND; ++k)
    sum += __bfloat162float(hrow[k]) * __bfloat162float(Wb[(size_t)k * NH + col]);
  sum += loadf(bb, col, *flag);
  beta[(size_t)row * NH + col] = 1.f / (1.f + expf(-sum));
}

// ---------------- in-place L2 norm over each 64-elem head segment (bf16) ----------------
__global__ __launch_bounds__(256) void l2norm_bf16(bf16* __restrict__ x) {
  const size_t rh = (size_t)blockIdx.x * 4 + (threadIdx.x >> 6);
  const int lane = threadIdx.x & 63;
  const float v = __bfloat162float(x[rh * 64 + lane]);
  float s = v * v;
  #pragma unroll
  for (int m = 32; m >= 1; m >>= 1) s += __shfl_xor(s, m, 64);
  x[rh * 64 + lane] = __float2bfloat16(v / sqrtf(s + 1e-6f));
}

// ---------------- pass 1: per-chunk local delta-rule scan (S0 = 0) ----------------
// Grid: NB*NH*NCH blocks, 128 threads (2 waves). Wave 0: values = v rows, writes
// u_t IN PLACE over v16. Wave 1: values = k rows, writes -g_t to Gneg[ch][t][d].
__global__ __launch_bounds__(128) void chunk_scan(const bf16* __restrict__ k16,
                                                  bf16* v16,
                                                  const float* __restrict__ beta,
                                                  bf16* __restrict__ Gneg) {
  const int ch = blockIdx.x;
  const int c = ch & (NCH - 1), bh = ch >> 5;
  const int h = bh & (NH - 1), b = bh >> 5;
  const int wave = threadIdx.x >> 6, lane = threadIdx.x & 63;
  const int t0 = c * 64;
  float S[64];
  #pragma unroll
  for (int i = 0; i < 64; ++i) S[i] = 0.f;
  bf16* gout = Gneg + (size_t)ch * 4096;
  #pragma unroll 1
  for (int t = 0; t < 64; ++t) {
    const size_t row = ((size_t)b * NT + t0 + t) * ND + (size_t)h * 64;
    const uint4* kp = (const uint4*)(k16 + row);   // wave-uniform -> broadcast
    uint4 ku[8];
    #pragma unroll
    for (int i = 0; i < 8; ++i) ku[i] = kp[i];
    const float val = __bfloat162float(wave ? k16[row + lane] : v16[row + lane]);
    const float bt = beta[((size_t)b * NT + t0 + t) * NH + h];
    float kvf[64];
    #pragma unroll
    for (int i = 0; i < 8; ++i) {
      kvf[8*i+0] = __uint_as_float(ku[i].x << 16);
      kvf[8*i+1] = __uint_as_float(ku[i].x & 0xffff0000u);
      kvf[8*i+2] = __uint_as_float(ku[i].y << 16);
      kvf[8*i+3] = __uint_as_float(ku[i].y & 0xffff0000u);
      kvf[8*i+4] = __uint_as_float(ku[i].z << 16);
      kvf[8*i+5] = __uint_as_float(ku[i].z & 0xffff0000u);
      kvf[8*i+6] = __uint_as_float(ku[i].w << 16);
      kvf[8*i+7] = __uint_as_float(ku[i].w & 0xffff0000u);
    }
    float p0 = 0, p1 = 0, p2 = 0, p3 = 0;
    #pragma unroll
    for (int i = 0; i < 16; ++i) {
      p0 += kvf[4*i+0] * S[4*i+0];
      p1 += kvf[4*i+1] * S[4*i+1];
      p2 += kvf[4*i+2] * S[4*i+2];
      p3 += kvf[4*i+3] * S[4*i+3];
    }
    const float u = bt * (val - ((p0 + p1) + (p2 + p3)));
    #pragma unroll
    for (int i = 0; i < 16; ++i) {
      S[4*i+0] += kvf[4*i+0] * u;
      S[4*i+1] += kvf[4*i+1] * u;
      S[4*i+2] += kvf[4*i+2] * u;
      S[4*i+3] += kvf[4*i+3] * u;
    }
    if (wave) gout[t * 64 + lane] = __float2bfloat16(-u);
    else      v16[row + lane]     = __float2bfloat16(u);
  }
}

// ---------------- pass 2+3: sequential cross-chunk recurrence + outputs ----------------
// One block per (b,h): 4 waves. S^T master in fp32 accumulators (wave w owns dv rows
// [16w,16w+16)). Per chunk: U_c = U_local + Gneg*S; P = tril(QK^T); O = Q*S + P*U_c
// (in place over q16); S^T += U_c^T*K. All 16x16x32 bf16 MFMA; LDS round-trips for
// C/D-layout -> A/B-layout (pad 8 halfwords: rows stay 16B aligned).
__global__ __launch_bounds__(256) void chunk_seq(bf16* q16,
                                                 const bf16* __restrict__ k16,
                                                 const bf16* __restrict__ Ul,   // = v16
                                                 const bf16* __restrict__ Gneg) {
  __shared__ bf16 ST[64 * 72];   // S^T: [dv][d]
  __shared__ bf16 Ubt[64 * 72];  // U^T: [dv][C]
  __shared__ bf16 Pt[64 * 72];   // P:   [t][j]
  __shared__ bf16 KTl[64 * 72];  // K^T: [d][C]
  const int bh = blockIdx.x, h = bh & (NH - 1), b = bh >> 5;
  const int wave = threadIdx.x >> 6, lane = threadIdx.x & 63;
  const int frow = lane & 15, q4 = lane >> 4, fk = q4 * 8;
  const int cm = q4 * 4;   // C/D row base within a 16x16 tile
  for (int i = threadIdx.x; i < 64 * 72 / 2; i += 256) ((unsigned int*)ST)[i] = 0u;
  __syncthreads();
  f32x4 sacc[4];
  #pragma unroll
  for (int n = 0; n < 4; ++n)
    #pragma unroll
    for (int r = 0; r < 4; ++r) sacc[n][r] = 0.f;

  #pragma unroll 1
  for (int c = 0; c < NCH; ++c) {
    const bf16* Gc = Gneg + ((size_t)bh * NCH + c) * 4096;
    const size_t qkb = ((size_t)b * NT + c * 64) * ND + (size_t)h * 64;

    // KT fill: wave w handles d-group [16w,16w+16), lane = t (contiguous LDS writes)
    {
      short8 r0 = *(const short8*)(k16 + qkb + (size_t)lane * ND + 16 * wave);
      short8 r1 = *(const short8*)(k16 + qkb + (size_t)lane * ND + 16 * wave + 8);
      #pragma unroll
      for (int j = 0; j < 8; ++j) {
        KTl[(16 * wave + j) * 72 + lane]     = ((const bf16*)&r0)[j];
        KTl[(16 * wave + 8 + j) * 72 + lane] = ((const bf16*)&r1)[j];
      }
    }
    // ---- A: U_c slab rows [16w,16w+16): U = U_local + Gneg @ S  (B-frag = S^T = ST)
    short8 ga0 = *(const short8*)(Gc + (16 * wave + frow) * 64 + fk);
    short8 ga1 = *(const short8*)(Gc + (16 * wave + frow) * 64 + 32 + fk);
    #pragma unroll
    for (int n = 0; n < 4; ++n) {
      f32x4 acc;
      #pragma unroll
      for (int r = 0; r < 4; ++r)
        acc[r] = __bfloat162float(Ul[qkb + (size_t)(16 * wave + cm + r) * ND + 16 * n + frow]);
      acc = __builtin_amdgcn_mfma_f32_16x16x32_bf16(ga0, *(const short8*)(ST + (16 * n + frow) * 72 + fk), acc, 0, 0, 0);
      acc = __builtin_amdgcn_mfma_f32_16x16x32_bf16(ga1, *(const short8*)(ST + (16 * n + frow) * 72 + 32 + fk), acc, 0, 0, 0);
      #pragma unroll
      for (int r = 0; r < 4; ++r)
        Ubt[(16 * n + frow) * 72 + 16 * wave + cm + r] = __float2bfloat16(acc[r]);
    }
    __syncthreads();   // Ubt + KTl ready; ST still S_c
    // ---- B: P slab = tril(Q K^T)  (A = Q rows global, B^T = K rows global)
    short8 qa0 = *(const short8*)(q16 + qkb + (size_t)(16 * wave + frow) * ND + fk);
    short8 qa1 = *(const short8*)(q16 + qkb + (size_t)(16 * wave + frow) * ND + 32 + fk);
    #pragma unroll
    for (int n = 0; n < 4; ++n) {
      f32x4 acc;
      #pragma unroll
      for (int r = 0; r < 4; ++r) acc[r] = 0.f;
      acc = __builtin_amdgcn_mfma_f32_16x16x32_bf16(qa0, *(const short8*)(k16 + qkb + (size_t)(16 * n + frow) * ND + fk), acc, 0, 0, 0);
      acc = __builtin_amdgcn_mfma_f32_16x16x32_bf16(qa1, *(const short8*)(k16 + qkb + (size_t)(16 * n + frow) * ND + 32 + fk), acc, 0, 0, 0);
      #pragma unroll
      for (int r = 0; r < 4; ++r) {
        const int mg = 16 * wave + cm + r, ng = 16 * n + frow;
        Pt[mg * 72 + ng] = __float2bfloat16(ng <= mg ? acc[r] : 0.f);
      }
    }
    __syncthreads();   // Pt ready
    // ---- C: O slab = Q*S + P*U_c  -> q16 in place
    short8 pa0 = *(const short8*)(Pt + (16 * wave + frow) * 72 + fk);
    short8 pa1 = *(const short8*)(Pt + (16 * wave + frow) * 72 + 32 + fk);
    #pragma unroll
    for (int n = 0; n < 4; ++n) {
      f32x4 acc;
      #pragma unroll
      for (int r = 0; r < 4; ++r) acc[r] = 0.f;
      acc = __builtin_amdgcn_mfma_f32_16x16x32_bf16(qa0, *(const short8*)(ST + (16 * n + frow) * 72 + fk), acc, 0, 0, 0);
      acc = __builtin_amdgcn_mfma_f32_16x16x32_bf16(qa1, *(const short8*)(ST + (16 * n + frow) * 72 + 32 + fk), acc, 0, 0, 0);
      acc = __builtin_amdgcn_mfma_f32_16x16x32_bf16(pa0, *(const short8*)(Ubt + (16 * n + frow) * 72 + fk), acc, 0, 0, 0);
      acc = __builtin_amdgcn_mfma_f32_16x16x32_bf16(pa1, *(const short8*)(Ubt + (16 * n + frow) * 72 + 32 + fk), acc, 0, 0, 0);
      #pragma unroll
      for (int r = 0; r < 4; ++r)
        q16[qkb + (size_t)(16 * wave + cm + r) * ND + 16 * n + frow] = __float2bfloat16(acc[r]);
    }
    __syncthreads();   // all ST reads done before D rewrites it
    // ---- D: S^T += U^T K   (A = Ubt rows, B^T = K^T rows = KTl)
    short8 ua0 = *(const short8*)(Ubt + (16 * wave + frow) * 72 + fk);
    short8 ua1 = *(const short8*)(Ubt + (16 * wave + frow) * 72 + 32 + fk);
    #pragma unroll
    for (int n = 0; n < 4; ++n) {
      sacc[n] = __builtin_amdgcn_mfma_f32_16x16x32_bf16(ua0, *(const short8*)(KTl + (16 * n + frow) * 72 + fk), sacc[n], 0, 0, 0);
      sacc[n] = __builtin_amdgcn_mfma_f32_16x16x32_bf16(ua1, *(const short8*)(KTl + (16 * n + frow) * 72 + 32 + fk), sacc[n], 0, 0, 0);
      #pragma unroll
      for (int r = 0; r < 4; ++r)
        ST[(16 * wave + cm + r) * 72 + 16 * n + frow] = __float2bfloat16(sacc[n][r]);
    }
    __syncthreads();   // ST = S_{c+1}
  }
}

extern "C" void kernel_launch(void* const* d_in, const int* in_sizes, int n_in,
                              void* d_out, int out_size, void* d_ws, size_t ws_size,
                              hipStream_t stream) {
  const void* hs = d_in[0];
  const void* Wq = d_in[1];
  const void* Wk = d_in[2];
  const void* Wv = d_in[3];
  const void* Wb = d_in[4];
  const void* bb = d_in[5];
  const void* Wo = d_in[6];

  char* ws = (char*)d_ws;
  size_t off = 0;
  auto alloc = [&](size_t bytes) {
    void* p = ws + off;
    off += (bytes + 255) & ~(size_t)255;
    return p;
  };
  int*   flag   = (int*)  alloc(256);
  bf16*  Wt     = (bf16*) alloc((size_t)ND * ND * 2);    // 8 MB (reused for Wo at end)
  char*  hsG    = (char*) alloc((size_t)NM * ND * 2);    // 16 MB: hs16 early, Gneg later
  bf16*  hs16   = (bf16*)hsG;
  bf16*  Gneg   = (bf16*)hsG;   // alias: hs16 dead before chunk_scan writes Gneg
  bf16*  q16    = (bf16*) alloc((size_t)NM * ND * 2);    // 16 MB (O in place)
  bf16*  k16    = (bf16*) alloc((size_t)NM * ND * 2);    // 16 MB
  bf16*  v16    = (bf16*) alloc((size_t)NM * ND * 2);    // 16 MB (U_local in place)
  bf16*  Wb16   = (bf16*) alloc((size_t)ND * NH * 2);    // 128 KB
  float* betaws = (float*)alloc((size_t)NM * NH * 4);    // 512 KB
  // total ~72.6 MB == round-2 footprint

  const dim3 tgrid(ND / 64, ND / 64);
  const dim3 ggrid(ND / 128, NM / 128);

  detect_dtype<<<1, 64, 0, stream>>>((const unsigned short*)hs, flag);
  convert_bf16<<<(NM * ND) / (256 * 8), 256, 0, stream>>>(hs, hs16, (long)NM * ND, flag);

  transpose_cvt<<<tgrid, 256, 0, stream>>>(Wq, Wt, ND, ND, flag);
  gemm_bt<<<ggrid, 256, 0, stream>>>(hs16, Wt, q16, nullptr, nullptr, NM, ND, ND);
  transpose_cvt<<<tgrid, 256, 0, stream>>>(Wk, Wt, ND, ND, flag);
  gemm_bt<<<ggrid, 256, 0, stream>>>(hs16, Wt, k16, nullptr, nullptr, NM, ND, ND);
  transpose_cvt<<<tgrid, 256, 0, stream>>>(Wv, Wt, ND, ND, flag);
  gemm_bt<<<ggrid, 256, 0, stream>>>(hs16, Wt, v16, nullptr, nullptr, NM, ND, ND);

  convert_bf16<<<(ND * NH) / (256 * 8), 256, 0, stream>>>(Wb, Wb16, (long)ND * NH, flag);
  beta_kernel<<<NM / 8, 256, 0, stream>>>(hs16, Wb16, bb, betaws, flag);
  l2norm_bf16<<<NM * NH / 4, 256, 0, stream>>>(q16);
  l2norm_bf16<<<NM * NH / 4, 256, 0, stream>>>(k16);

  // hs16 dead from here on -> Gneg may overwrite its region
  chunk_scan<<<NB * NH * NCH, 128, 0, stream>>>(k16, v16, betaws, Gneg);
  chunk_seq<<<NB * NH, 256, 0, stream>>>(q16, k16, v16, Gneg);

  transpose_cvt<<<tgrid, 256, 0, stream>>>(Wo, Wt, ND, ND, flag);
  gemm_bt<<<ggrid, 256, 0, stream>>>(q16, Wt, nullptr, d_out, flag, NM, ND, ND);
}

// Round 4
// 778.883 us; speedup vs baseline: 5.4187x; 1.1172x over previous
//
#include <hip/hip_runtime.h>
#include <hip/hip_bf16.h>

typedef __hip_bfloat16 bf16;
typedef __attribute__((ext_vector_type(8))) short short8;   // 8 bf16 (4 VGPRs)
typedef __attribute__((ext_vector_type(4))) float f32x4;

#define NB 2
#define NT 2048
#define ND 2048
#define NH 32
#define NM (NB*NT)   // 4096 rows
#define NCH 32       // chunks per (b,h): NT/64

// ---- dtype hedge: inputs may be bf16 (harness-converted) or fp32 (per reference) ----
__global__ void detect_dtype(const unsigned short* __restrict__ hs, int* __restrict__ flag) {
  if (threadIdx.x == 0 && blockIdx.x == 0) {
    int cnt = 0;
    for (int i = 0; i < 2048; i += 2) {
      int e = (hs[i] >> 7) & 0xFF;
      if (e >= 141) ++cnt;
    }
    *flag = (cnt > 64) ? 1 : 0;   // 1 = fp32, 0 = bf16
  }
}

__device__ __forceinline__ float loadf(const void* p, size_t i, int isf32) {
  return isf32 ? ((const float*)p)[i] : __bfloat162float(((const bf16*)p)[i]);
}

__global__ __launch_bounds__(256) void convert_bf16(const void* __restrict__ src,
                                                    bf16* __restrict__ dst,
                                                    long n, const int* __restrict__ flag) {
  const long i0 = ((long)blockIdx.x * 256 + threadIdx.x) * 8;
  if (i0 >= n) return;
  if (*flag) {
    const float* s = (const float*)src;
    #pragma unroll
    for (int j = 0; j < 8; ++j) dst[i0 + j] = __float2bfloat16(s[i0 + j]);
  } else {
    *(short8*)(dst + i0) = *(const short8*)((const bf16*)src + i0);
  }
}

// ---- transpose + convert: dst[c][r] = bf16(src[r][c]); zero-pad cols >= src_cols ----
// grid: (dst_rows/64, src_rows/64). dst row stride = src_rows.
__global__ __launch_bounds__(256) void transpose_cvt(const void* __restrict__ src,
                                                     bf16* __restrict__ dst,
                                                     int src_rows, int src_cols,
                                                     const int* __restrict__ flag) {
  __shared__ bf16 tile[64][65];
  const int f = *flag;
  const int tb_r = blockIdx.y * 64, tb_c = blockIdx.x * 64;
  const int tx = threadIdx.x & 63, ty = threadIdx.x >> 6;
  #pragma unroll
  for (int i = 0; i < 64; i += 4) {
    const int cc = tb_c + tx;
    tile[i + ty][tx] = (cc < src_cols)
      ? __float2bfloat16(loadf(src, (size_t)(tb_r + i + ty) * src_cols + cc, f))
      : __float2bfloat16(0.f);
  }
  __syncthreads();
  #pragma unroll
  for (int i = 0; i < 64; i += 4)
    dst[(size_t)(tb_c + i + ty) * src_rows + tb_r + tx] = tile[tx][i + ty];
}

// async 16B/lane global->LDS (wave-uniform LDS base + lane*16)
__device__ __forceinline__ void gload_lds16(const void* g, void* l) {
  __builtin_amdgcn_global_load_lds((__attribute__((address_space(1))) const void*)g,
                                   (__attribute__((address_space(3))) void*)l,
                                   16, 0, 0);
}

// ------------- GEMM: C = A[M][K] @ Bt[n][K]^T  (bf16 in, fp32 acc) -------------
// outflag == null: routed epilogue by global col gn = n_base + n0:
//   seg = gn>>11: 0->oq, 1->ok, 2->ov (stride 2048), 3->ob (stride 128).
// outflag != null: write outv (fp32/bf16 per *outflag), stride 2048.
__global__ __launch_bounds__(256) void gemm_bt(const bf16* __restrict__ A,
                                               const bf16* __restrict__ Bt,
                                               bf16* __restrict__ oq, bf16* __restrict__ ok2,
                                               bf16* __restrict__ ov, bf16* __restrict__ ob,
                                               void* __restrict__ outv,
                                               const int* __restrict__ outflag,
                                               int M, int K, int n_base) {
  __shared__ bf16 As[128 * 32];
  __shared__ bf16 Bs[128 * 32];
  const int tid = threadIdx.x;
  const int wave = tid >> 6, lane = tid & 63;
  const int m0 = blockIdx.y * 128, n0 = blockIdx.x * 128;
  const int wm = (wave >> 1) * 64, wn = (wave & 1) * 64;
  const int srow = lane >> 2, scol = (lane & 3) * 8;
  const int frow = lane & 15, fk = (lane >> 4) * 8;
  f32x4 acc[4][4] = {};

  for (int kb = 0; kb < K; kb += 32) {
    __syncthreads();
    #pragma unroll
    for (int j = 0; j < 2; ++j) {
      const int rbase = wave * 32 + j * 16;
      gload_lds16(A  + (size_t)(m0 + rbase + srow) * K + kb + scol, As + rbase * 32);
      gload_lds16(Bt + (size_t)(n0 + rbase + srow) * K + kb + scol, Bs + rbase * 32);
    }
    __syncthreads();
    short8 af[4], bfr[4];
    #pragma unroll
    for (int i = 0; i < 4; ++i)
      af[i] = *(const short8*)(As + (wm + i * 16 + frow) * 32 + fk);
    #pragma unroll
    for (int i = 0; i < 4; ++i)
      bfr[i] = *(const short8*)(Bs + (wn + i * 16 + frow) * 32 + fk);
    #pragma unroll
    for (int mi = 0; mi < 4; ++mi)
      #pragma unroll
      for (int ni = 0; ni < 4; ++ni)
        acc[mi][ni] = __builtin_amdgcn_mfma_f32_16x16x32_bf16(af[mi], bfr[ni], acc[mi][ni], 0, 0, 0);
  }

  // C/D layout: col = lane&15, row = (lane>>4)*4 + reg  [m89-verified]
  const int crow = (lane >> 4) * 4, ccol = lane & 15;
  const int gn0 = n_base + n0;
  if (outflag) {
    const int f = *outflag;
    #pragma unroll
    for (int mi = 0; mi < 4; ++mi)
      #pragma unroll
      for (int ni = 0; ni < 4; ++ni)
        #pragma unroll
        for (int r = 0; r < 4; ++r) {
          const size_t idx = (size_t)(m0 + wm + mi * 16 + crow + r) * 2048 + gn0 + wn + ni * 16 + ccol;
          const float val = acc[mi][ni][r];
          if (f == 1) ((float*)outv)[idx] = val;
          else        ((bf16*)outv)[idx] = __float2bfloat16(val);
        }
  } else {
    const int seg = gn0 >> 11;
    bf16* o = (seg == 0) ? oq : (seg == 1) ? ok2 : (seg == 2) ? ov : ob;
    const int stride = (seg < 3) ? 2048 : 128;
    const int cb = (gn0 & 2047) + wn;
    #pragma unroll
    for (int mi = 0; mi < 4; ++mi)
      #pragma unroll
      for (int ni = 0; ni < 4; ++ni)
        #pragma unroll
        for (int r = 0; r < 4; ++r)
          o[(size_t)(m0 + wm + mi * 16 + crow + r) * stride + cb + ni * 16 + ccol] =
            __float2bfloat16(acc[mi][ni][r]);
  }
}

// ---------------- in-place L2 norm over each 64-elem head segment (bf16) ----------------
__global__ __launch_bounds__(256) void l2norm_bf16(bf16* __restrict__ x) {
  const size_t rh = (size_t)blockIdx.x * 4 + (threadIdx.x >> 6);
  const int lane = threadIdx.x & 63;
  const float v = __bfloat162float(x[rh * 64 + lane]);
  float s = v * v;
  #pragma unroll
  for (int m = 32; m >= 1; m >>= 1) s += __shfl_xor(s, m, 64);
  x[rh * 64 + lane] = __float2bfloat16(v / sqrtf(s + 1e-6f));
}

// ---------------- pass 1: per-chunk local delta-rule scan (S0 = 0), LDS-staged ----------------
// Grid NB*NH*NCH, 128 threads (2 waves). Stages K,V chunks + beta logits into LDS;
// wave 0 scans values=v -> U_local (in place over v16); wave 1 scans values=k -> -G.
// Beta: sigmoid(logit + bias) computed here (betab holds pre-activation bf16 logits).
__global__ __launch_bounds__(128) void chunk_scan(const bf16* __restrict__ k16,
                                                  bf16* __restrict__ v16,
                                                  const bf16* __restrict__ betab,
                                                  const void* __restrict__ bb,
                                                  const int* __restrict__ flag,
                                                  bf16* __restrict__ Gneg) {
  __shared__ bf16 Ks[64 * 64];
  __shared__ bf16 Vs[64 * 64];   // V in, U out (in place)
  __shared__ bf16 Gs[64 * 64];
  __shared__ float Bs[64];
  const int ch = blockIdx.x;
  const int c = ch & (NCH - 1), bh = ch >> 5;
  const int h = bh & (NH - 1), b = bh >> 5;
  const int tid = threadIdx.x;
  const int wave = tid >> 6, lane = tid & 63;
  const size_t rowb = ((size_t)b * NT + c * 64) * ND + (size_t)h * 64;
  const int sr = tid >> 3, sc = (tid & 7) * 8;
  #pragma unroll
  for (int rnd = 0; rnd < 4; ++rnd) {
    const int r = rnd * 16 + sr;
    *(short8*)(Ks + r * 64 + sc) = *(const short8*)(k16 + rowb + (size_t)r * ND + sc);
    *(short8*)(Vs + r * 64 + sc) = *(const short8*)(v16 + rowb + (size_t)r * ND + sc);
  }
  if (tid < 64) {
    const float x = __bfloat162float(betab[((size_t)b * NT + c * 64 + tid) * 128 + h])
                    + loadf(bb, h, *flag);
    Bs[tid] = 1.f / (1.f + expf(-x));
  }
  __syncthreads();
  float S[64];
  #pragma unroll
  for (int i = 0; i < 64; ++i) S[i] = 0.f;
  const bf16* val_src = wave ? Ks : Vs;
  #pragma unroll 1
  for (int t = 0; t < 64; ++t) {
    uint4 ku[8];
    #pragma unroll
    for (int i = 0; i < 8; ++i) ku[i] = ((const uint4*)(Ks + t * 64))[i];   // wave-uniform
    const float val = __bfloat162float(val_src[t * 64 + lane]);
    const float bt = Bs[t];
    float kvf[64];
    #pragma unroll
    for (int i = 0; i < 8; ++i) {
      kvf[8*i+0] = __uint_as_float(ku[i].x << 16);
      kvf[8*i+1] = __uint_as_float(ku[i].x & 0xffff0000u);
      kvf[8*i+2] = __uint_as_float(ku[i].y << 16);
      kvf[8*i+3] = __uint_as_float(ku[i].y & 0xffff0000u);
      kvf[8*i+4] = __uint_as_float(ku[i].z << 16);
      kvf[8*i+5] = __uint_as_float(ku[i].z & 0xffff0000u);
      kvf[8*i+6] = __uint_as_float(ku[i].w << 16);
      kvf[8*i+7] = __uint_as_float(ku[i].w & 0xffff0000u);
    }
    float p0 = 0, p1 = 0, p2 = 0, p3 = 0;
    #pragma unroll
    for (int i = 0; i < 16; ++i) {
      p0 += kvf[4*i+0] * S[4*i+0];
      p1 += kvf[4*i+1] * S[4*i+1];
      p2 += kvf[4*i+2] * S[4*i+2];
      p3 += kvf[4*i+3] * S[4*i+3];
    }
    const float u = bt * (val - ((p0 + p1) + (p2 + p3)));
    #pragma unroll
    for (int i = 0; i < 16; ++i) {
      S[4*i+0] += kvf[4*i+0] * u;
      S[4*i+1] += kvf[4*i+1] * u;
      S[4*i+2] += kvf[4*i+2] * u;
      S[4*i+3] += kvf[4*i+3] * u;
    }
    if (wave) Gs[t * 64 + lane] = __float2bfloat16(-u);
    else      Vs[t * 64 + lane] = __float2bfloat16(u);
  }
  __syncthreads();
  bf16* gout = Gneg + (size_t)ch * 4096;
  #pragma unroll
  for (int rnd = 0; rnd < 4; ++rnd) {
    const int r = rnd * 16 + sr;
    *(short8*)(v16 + rowb + (size_t)r * ND + sc) = *(const short8*)(Vs + r * 64 + sc);
    *(short8*)(gout + r * 64 + sc)               = *(const short8*)(Gs + r * 64 + sc);
  }
}

// ---------------- pass 2: minimal sequential recurrence ----------------
// One block per (b,h), 4 waves. Per chunk: save T_c = S_c^T to Sbuf; U_c = U_local +
// Gneg*S_c (phase A, written in place over v16); T += U^T K (phase D). 2 barriers/chunk.
__global__ __launch_bounds__(256) void state_seq(const bf16* __restrict__ k16,
                                                 bf16* __restrict__ Ul,      // v16: U_local in, U_c out
                                                 const bf16* __restrict__ Gneg,
                                                 bf16* __restrict__ Sbuf) {
  __shared__ bf16 ST[64 * 72];
  __shared__ bf16 Ubt[64 * 72];
  __shared__ bf16 KTl[64 * 72];
  const int bh = blockIdx.x, h = bh & (NH - 1), b = bh >> 5;
  const int wave = threadIdx.x >> 6, lane = threadIdx.x & 63;
  const int frow = lane & 15, q4 = lane >> 4, fk = q4 * 8, cm = q4 * 4;
  for (int i = threadIdx.x; i < 64 * 72 / 2; i += 256) ((unsigned int*)ST)[i] = 0u;
  __syncthreads();
  f32x4 sacc[4];
  #pragma unroll
  for (int n = 0; n < 4; ++n)
    #pragma unroll
    for (int r = 0; r < 4; ++r) sacc[n][r] = 0.f;
  const int cr = threadIdx.x >> 2, cs = (threadIdx.x & 3) * 16;

  #pragma unroll 1
  for (int c = 0; c < NCH; ++c) {
    const bf16* Gc = Gneg + ((size_t)bh * NCH + c) * 4096;
    const size_t qkb = ((size_t)b * NT + c * 64) * ND + (size_t)h * 64;
    // save pre-state T_c to Sbuf (row-major [v][d], stride 64)
    bf16* sb = Sbuf + ((size_t)bh * NCH + c) * 4096;
    *(short8*)(sb + cr * 64 + cs)     = *(const short8*)(ST + cr * 72 + cs);
    *(short8*)(sb + cr * 64 + cs + 8) = *(const short8*)(ST + cr * 72 + cs + 8);
    // K^T fill
    {
      short8 r0 = *(const short8*)(k16 + qkb + (size_t)lane * ND + 16 * wave);
      short8 r1 = *(const short8*)(k16 + qkb + (size_t)lane * ND + 16 * wave + 8);
      #pragma unroll
      for (int j = 0; j < 8; ++j) {
        KTl[(16 * wave + j) * 72 + lane]     = ((const bf16*)&r0)[j];
        KTl[(16 * wave + 8 + j) * 72 + lane] = ((const bf16*)&r1)[j];
      }
    }
    // phase A: U = U_local + Gneg @ S  (B-frag = S^T rows = ST)
    short8 ga0 = *(const short8*)(Gc + (16 * wave + frow) * 64 + fk);
    short8 ga1 = *(const short8*)(Gc + (16 * wave + frow) * 64 + 32 + fk);
    f32x4 ua[4];
    #pragma unroll
    for (int n = 0; n < 4; ++n)
      #pragma unroll
      for (int r = 0; r < 4; ++r)
        ua[n][r] = __bfloat162float(Ul[qkb + (size_t)(16 * wave + cm + r) * ND + 16 * n + frow]);
    #pragma unroll
    for (int n = 0; n < 4; ++n) {
      ua[n] = __builtin_amdgcn_mfma_f32_16x16x32_bf16(ga0, *(const short8*)(ST + (16 * n + frow) * 72 + fk), ua[n], 0, 0, 0);
      ua[n] = __builtin_amdgcn_mfma_f32_16x16x32_bf16(ga1, *(const short8*)(ST + (16 * n + frow) * 72 + 32 + fk), ua[n], 0, 0, 0);
      #pragma unroll
      for (int r = 0; r < 4; ++r) {
        const bf16 uv = __float2bfloat16(ua[n][r]);
        Ubt[(16 * n + frow) * 72 + 16 * wave + cm + r] = uv;          // U^T for phase D
        Ul[qkb + (size_t)(16 * wave + cm + r) * ND + 16 * n + frow] = uv;  // U_c for chunk_out
      }
    }
    __syncthreads();   // Ubt,KTl ready; all ST reads done
    // phase D: T += U^T K
    short8 ua0 = *(const short8*)(Ubt + (16 * wave + frow) * 72 + fk);
    short8 ua1 = *(const short8*)(Ubt + (16 * wave + frow) * 72 + 32 + fk);
    #pragma unroll
    for (int n = 0; n < 4; ++n) {
      sacc[n] = __builtin_amdgcn_mfma_f32_16x16x32_bf16(ua0, *(const short8*)(KTl + (16 * n + frow) * 72 + fk), sacc[n], 0, 0, 0);
      sacc[n] = __builtin_amdgcn_mfma_f32_16x16x32_bf16(ua1, *(const short8*)(KTl + (16 * n + frow) * 72 + 32 + fk), sacc[n], 0, 0, 0);
      #pragma unroll
      for (int r = 0; r < 4; ++r)
        ST[(16 * wave + cm + r) * 72 + 16 * n + frow] = __float2bfloat16(sacc[n][r]);
    }
    __syncthreads();   // ST = T_{c+1}
  }
}

// ---------------- pass 3: chunk-parallel outputs ----------------
// Grid NB*NH*NCH, 4 waves. O = Q*S_c + tril(QK^T)*U_c, written in place over q16.
__global__ __launch_bounds__(256) void chunk_out(bf16* __restrict__ q16,
                                                 const bf16* __restrict__ k16,
                                                 const bf16* __restrict__ Uc,   // v16
                                                 const bf16* __restrict__ Sbuf) {
  __shared__ bf16 Pt[64 * 72];
  __shared__ bf16 UT[64 * 72];
  const int ch = blockIdx.x;
  const int c = ch & (NCH - 1), bh = ch >> 5;
  const int h = bh & (NH - 1), b = bh >> 5;
  const int wave = threadIdx.x >> 6, lane = threadIdx.x & 63;
  const int frow = lane & 15, q4 = lane >> 4, fk = q4 * 8, cm = q4 * 4;
  const size_t qkb = ((size_t)b * NT + c * 64) * ND + (size_t)h * 64;
  const bf16* Sb = Sbuf + (size_t)ch * 4096;
  // U^T fill
  {
    short8 u0 = *(const short8*)(Uc + qkb + (size_t)lane * ND + 16 * wave);
    short8 u1 = *(const short8*)(Uc + qkb + (size_t)lane * ND + 16 * wave + 8);
    #pragma unroll
    for (int j = 0; j < 8; ++j) {
      UT[(16 * wave + j) * 72 + lane]     = ((const bf16*)&u0)[j];
      UT[(16 * wave + 8 + j) * 72 + lane] = ((const bf16*)&u1)[j];
    }
  }
  short8 qa0 = *(const short8*)(q16 + qkb + (size_t)(16 * wave + frow) * ND + fk);
  short8 qa1 = *(const short8*)(q16 + qkb + (size_t)(16 * wave + frow) * ND + 32 + fk);
  // P = tril(Q K^T) (inclusive diagonal)
  #pragma unroll
  for (int n = 0; n < 4; ++n) {
    f32x4 acc;
    #pragma unroll
    for (int r = 0; r < 4; ++r) acc[r] = 0.f;
    acc = __builtin_amdgcn_mfma_f32_16x16x32_bf16(qa0, *(const short8*)(k16 + qkb + (size_t)(16 * n + frow) * ND + fk), acc, 0, 0, 0);
    acc = __builtin_amdgcn_mfma_f32_16x16x32_bf16(qa1, *(const short8*)(k16 + qkb + (size_t)(16 * n + frow) * ND + 32 + fk), acc, 0, 0, 0);
    #pragma unroll
    for (int r = 0; r < 4; ++r) {
      const int mg = 16 * wave + cm + r, ng = 16 * n + frow;
      Pt[mg * 72 + ng] = __float2bfloat16(ng <= mg ? acc[r] : 0.f);
    }
  }
  __syncthreads();
  // O = Q*S + P*U
  short8 pa0 = *(const short8*)(Pt + (16 * wave + frow) * 72 + fk);
  short8 pa1 = *(const short8*)(Pt + (16 * wave + frow) * 72 + 32 + fk);
  #pragma unroll
  for (int n = 0; n < 4; ++n) {
    f32x4 acc;
    #pragma unroll
    for (int r = 0; r < 4; ++r) acc[r] = 0.f;
    acc = __builtin_amdgcn_mfma_f32_16x16x32_bf16(qa0, *(const short8*)(Sb + (16 * n + frow) * 64 + fk), acc, 0, 0, 0);
    acc = __builtin_amdgcn_mfma_f32_16x16x32_bf16(qa1, *(const short8*)(Sb + (16 * n + frow) * 64 + 32 + fk), acc, 0, 0, 0);
    acc = __builtin_amdgcn_mfma_f32_16x16x32_bf16(pa0, *(const short8*)(UT + (16 * n + frow) * 72 + fk), acc, 0, 0, 0);
    acc = __builtin_amdgcn_mfma_f32_16x16x32_bf16(pa1, *(const short8*)(UT + (16 * n + frow) * 72 + 32 + fk), acc, 0, 0, 0);
    #pragma unroll
    for (int r = 0; r < 4; ++r)
      q16[qkb + (size_t)(16 * wave + cm + r) * ND + 16 * n + frow] = __float2bfloat16(acc[r]);
  }
}

// ---------------- fallback: round-3 monolithic sequential kernel (verbatim) ----------------
__global__ __launch_bounds__(256) void chunk_seq_mono(bf16* q16,
                                                      const bf16* __restrict__ k16,
                                                      const bf16* __restrict__ Ul,
                                                      const bf16* __restrict__ Gneg) {
  __shared__ bf16 ST[64 * 72];
  __shared__ bf16 Ubt[64 * 72];
  __shared__ bf16 Pt[64 * 72];
  __shared__ bf16 KTl[64 * 72];
  const int bh = blockIdx.x, h = bh & (NH - 1), b = bh >> 5;
  const int wave = threadIdx.x >> 6, lane = threadIdx.x & 63;
  const int frow = lane & 15, q4 = lane >> 4, fk = q4 * 8;
  const int cm = q4 * 4;
  for (int i = threadIdx.x; i < 64 * 72 / 2; i += 256) ((unsigned int*)ST)[i] = 0u;
  __syncthreads();
  f32x4 sacc[4];
  #pragma unroll
  for (int n = 0; n < 4; ++n)
    #pragma unroll
    for (int r = 0; r < 4; ++r) sacc[n][r] = 0.f;

  #pragma unroll 1
  for (int c = 0; c < NCH; ++c) {
    const bf16* Gc = Gneg + ((size_t)bh * NCH + c) * 4096;
    const size_t qkb = ((size_t)b * NT + c * 64) * ND + (size_t)h * 64;
    {
      short8 r0 = *(const short8*)(k16 + qkb + (size_t)lane * ND + 16 * wave);
      short8 r1 = *(const short8*)(k16 + qkb + (size_t)lane * ND + 16 * wave + 8);
      #pragma unroll
      for (int j = 0; j < 8; ++j) {
        KTl[(16 * wave + j) * 72 + lane]     = ((const bf16*)&r0)[j];
        KTl[(16 * wave + 8 + j) * 72 + lane] = ((const bf16*)&r1)[j];
      }
    }
    short8 ga0 = *(const short8*)(Gc + (16 * wave + frow) * 64 + fk);
    short8 ga1 = *(const short8*)(Gc + (16 * wave + frow) * 64 + 32 + fk);
    #pragma unroll
    for (int n = 0; n < 4; ++n) {
      f32x4 acc;
      #pragma unroll
      for (int r = 0; r < 4; ++r)
        acc[r] = __bfloat162float(Ul[qkb + (size_t)(16 * wave + cm + r) * ND + 16 * n + frow]);
      acc = __builtin_amdgcn_mfma_f32_16x16x32_bf16(ga0, *(const short8*)(ST + (16 * n + frow) * 72 + fk), acc, 0, 0, 0);
      acc = __builtin_amdgcn_mfma_f32_16x16x32_bf16(ga1, *(const short8*)(ST + (16 * n + frow) * 72 + 32 + fk), acc, 0, 0, 0);
      #pragma unroll
      for (int r = 0; r < 4; ++r)
        Ubt[(16 * n + frow) * 72 + 16 * wave + cm + r] = __float2bfloat16(acc[r]);
    }
    __syncthreads();
    short8 qa0 = *(const short8*)(q16 + qkb + (size_t)(16 * wave + frow) * ND + fk);
    short8 qa1 = *(const short8*)(q16 + qkb + (size_t)(16 * wave + frow) * ND + 32 + fk);
    #pragma unroll
    for (int n = 0; n < 4; ++n) {
      f32x4 acc;
      #pragma unroll
      for (int r = 0; r < 4; ++r) acc[r] = 0.f;
      acc = __builtin_amdgcn_mfma_f32_16x16x32_bf16(qa0, *(const short8*)(k16 + qkb + (size_t)(16 * n + frow) * ND + fk), acc, 0, 0, 0);
      acc = __builtin_amdgcn_mfma_f32_16x16x32_bf16(qa1, *(const short8*)(k16 + qkb + (size_t)(16 * n + frow) * ND + 32 + fk), acc, 0, 0, 0);
      #pragma unroll
      for (int r = 0; r < 4; ++r) {
        const int mg = 16 * wave + cm + r, ng = 16 * n + frow;
        Pt[mg * 72 + ng] = __float2bfloat16(ng <= mg ? acc[r] : 0.f);
      }
    }
    __syncthreads();
    short8 pa0 = *(const short8*)(Pt + (16 * wave + frow) * 72 + fk);
    short8 pa1 = *(const short8*)(Pt + (16 * wave + frow) * 72 + 32 + fk);
    #pragma unroll
    for (int n = 0; n < 4; ++n) {
      f32x4 acc;
      #pragma unroll
      for (int r = 0; r < 4; ++r) acc[r] = 0.f;
      acc = __builtin_amdgcn_mfma_f32_16x16x32_bf16(qa0, *(const short8*)(ST + (16 * n + frow) * 72 + fk), acc, 0, 0, 0);
      acc = __builtin_amdgcn_mfma_f32_16x16x32_bf16(qa1, *(const short8*)(ST + (16 * n + frow) * 72 + 32 + fk), acc, 0, 0, 0);
      acc = __builtin_amdgcn_mfma_f32_16x16x32_bf16(pa0, *(const short8*)(Ubt + (16 * n + frow) * 72 + fk), acc, 0, 0, 0);
      acc = __builtin_amdgcn_mfma_f32_16x16x32_bf16(pa1, *(const short8*)(Ubt + (16 * n + frow) * 72 + 32 + fk), acc, 0, 0, 0);
      #pragma unroll
      for (int r = 0; r < 4; ++r)
        q16[qkb + (size_t)(16 * wave + cm + r) * ND + 16 * n + frow] = __float2bfloat16(acc[r]);
    }
    __syncthreads();
    short8 ua0 = *(const short8*)(Ubt + (16 * wave + frow) * 72 + fk);
    short8 ua1 = *(const short8*)(Ubt + (16 * wave + frow) * 72 + 32 + fk);
    #pragma unroll
    for (int n = 0; n < 4; ++n) {
      sacc[n] = __builtin_amdgcn_mfma_f32_16x16x32_bf16(ua0, *(const short8*)(KTl + (16 * n + frow) * 72 + fk), sacc[n], 0, 0, 0);
      sacc[n] = __builtin_amdgcn_mfma_f32_16x16x32_bf16(ua1, *(const short8*)(KTl + (16 * n + frow) * 72 + 32 + fk), sacc[n], 0, 0, 0);
      #pragma unroll
      for (int r = 0; r < 4; ++r)
        ST[(16 * wave + cm + r) * 72 + 16 * n + frow] = __float2bfloat16(sacc[n][r]);
    }
    __syncthreads();
  }
}

extern "C" void kernel_launch(void* const* d_in, const int* in_sizes, int n_in,
                              void* d_out, int out_size, void* d_ws, size_t ws_size,
                              hipStream_t stream) {
  const void* hs = d_in[0];
  const void* Wq = d_in[1];
  const void* Wk = d_in[2];
  const void* Wv = d_in[3];
  const void* Wb = d_in[4];
  const void* bb = d_in[5];
  const void* Wo = d_in[6];

  char* ws = (char*)d_ws;
  size_t off = 0;
  auto alloc = [&](size_t bytes) {
    void* p = ws + off;
    off += (bytes + 255) & ~(size_t)255;
    return p;
  };
  const size_t szW  = (size_t)6272 * 2048 * 2;   // 24.5 MB (Wqkvb^T, padded beta cols)
  const size_t szM  = (size_t)NM * ND * 2;       // 16 MB
  const size_t szB  = (size_t)NM * 128 * 2;      // 1 MB (beta logits, 128-padded)
  const size_t need_fused = 512 + szW + 4 * szM + szB;   // ~89.6 MB

  if (ws_size >= need_fused) {
    // ---- fused path ----
    int*  flag  = (int*) alloc(256);
    bf16* WT    = (bf16*)alloc(szW);   // later: Gneg (first 16 MB) + WoT (at +16 MB)
    bf16* hs16  = (bf16*)alloc(szM);   // later: Sbuf
    bf16* q16   = (bf16*)alloc(szM);
    bf16* k16   = (bf16*)alloc(szM);
    bf16* v16   = (bf16*)alloc(szM);
    bf16* betab = (bf16*)alloc(szB);
    bf16* Gneg  = WT;                                    // WT dead after fused GEMM
    bf16* WoT   = WT + (size_t)8 * 1024 * 1024;          // +16 MB (8M elements)
    bf16* Sbuf  = hs16;                                  // hs16 dead after fused GEMM

    detect_dtype<<<1, 64, 0, stream>>>((const unsigned short*)hs, flag);
    convert_bf16<<<(NM * ND) / (256 * 8), 256, 0, stream>>>(hs, hs16, (long)NM * ND, flag);

    transpose_cvt<<<dim3(32, 32), 256, 0, stream>>>(Wq, WT,                         2048, 2048, flag);
    transpose_cvt<<<dim3(32, 32), 256, 0, stream>>>(Wk, WT + (size_t)2048 * 2048,   2048, 2048, flag);
    transpose_cvt<<<dim3(32, 32), 256, 0, stream>>>(Wv, WT + (size_t)2 * 2048 * 2048, 2048, 2048, flag);
    transpose_cvt<<<dim3(2, 32),  256, 0, stream>>>(Wb, WT + (size_t)3 * 2048 * 2048, 2048, 32, flag);

    gemm_bt<<<dim3(49, 32), 256, 0, stream>>>(hs16, WT, q16, k16, v16, betab,
                                              nullptr, nullptr, NM, ND, 0);

    l2norm_bf16<<<NM * NH / 4, 256, 0, stream>>>(q16);
    l2norm_bf16<<<NM * NH / 4, 256, 0, stream>>>(k16);

    chunk_scan<<<NB * NH * NCH, 128, 0, stream>>>(k16, v16, betab, bb, flag, Gneg);
    state_seq<<<NB * NH, 256, 0, stream>>>(k16, v16, Gneg, Sbuf);
    chunk_out<<<NB * NH * NCH, 256, 0, stream>>>(q16, k16, v16, Sbuf);

    transpose_cvt<<<dim3(32, 32), 256, 0, stream>>>(Wo, WoT, 2048, 2048, flag);
    gemm_bt<<<dim3(16, 32), 256, 0, stream>>>(q16, WoT, nullptr, nullptr, nullptr, nullptr,
                                              d_out, flag, NM, ND, 0);
  } else {
    // ---- compact fallback (proven ~73 MB footprint) ----
    int*  flag  = (int*) alloc(256);
    bf16* Wt    = (bf16*)alloc((size_t)2048 * 2048 * 2);   // 8 MB, reused per weight
    bf16* hs16  = (bf16*)alloc(szM);                       // later: Gneg
    bf16* q16   = (bf16*)alloc(szM);
    bf16* k16   = (bf16*)alloc(szM);
    bf16* v16   = (bf16*)alloc(szM);
    bf16* betab = (bf16*)alloc(szB);
    bf16* Gneg  = hs16;

    detect_dtype<<<1, 64, 0, stream>>>((const unsigned short*)hs, flag);
    convert_bf16<<<(NM * ND) / (256 * 8), 256, 0, stream>>>(hs, hs16, (long)NM * ND, flag);

    transpose_cvt<<<dim3(32, 32), 256, 0, stream>>>(Wq, Wt, 2048, 2048, flag);
    gemm_bt<<<dim3(16, 32), 256, 0, stream>>>(hs16, Wt, q16, k16, v16, betab, nullptr, nullptr, NM, ND, 0);
    transpose_cvt<<<dim3(32, 32), 256, 0, stream>>>(Wk, Wt, 2048, 2048, flag);
    gemm_bt<<<dim3(16, 32), 256, 0, stream>>>(hs16, Wt, q16, k16, v16, betab, nullptr, nullptr, NM, ND, 2048);
    transpose_cvt<<<dim3(32, 32), 256, 0, stream>>>(Wv, Wt, 2048, 2048, flag);
    gemm_bt<<<dim3(16, 32), 256, 0, stream>>>(hs16, Wt, q16, k16, v16, betab, nullptr, nullptr, NM, ND, 4096);
    transpose_cvt<<<dim3(2, 32),  256, 0, stream>>>(Wb, Wt, 2048, 32, flag);
    gemm_bt<<<dim3(1, 32), 256, 0, stream>>>(hs16, Wt, q16, k16, v16, betab, nullptr, nullptr, NM, ND, 6144);

    l2norm_bf16<<<NM * NH / 4, 256, 0, stream>>>(q16);
    l2norm_bf16<<<NM * NH / 4, 256, 0, stream>>>(k16);

    chunk_scan<<<NB * NH * NCH, 128, 0, stream>>>(k16, v16, betab, bb, flag, Gneg);
    chunk_seq_mono<<<NB * NH, 256, 0, stream>>>(q16, k16, v16, Gneg);

    transpose_cvt<<<dim3(32, 32), 256, 0, stream>>>(Wo, Wt, 2048, 2048, flag);
    gemm_bt<<<dim3(16, 32), 256, 0, stream>>>(q16, Wt, nullptr, nullptr, nullptr, nullptr,
                                              d_out, flag, NM, ND, 0);
  }
}

// Round 5
// 670.434 us; speedup vs baseline: 6.2953x; 1.1618x over previous
//
#include <hip/hip_runtime.h>
#include <hip/hip_bf16.h>

typedef __hip_bfloat16 bf16;
typedef __attribute__((ext_vector_type(8))) short short8;   // 8 bf16 (4 VGPRs)
typedef __attribute__((ext_vector_type(4))) float f32x4;

#define NB 2
#define NT 2048
#define ND 2048
#define NH 32
#define NM (NB*NT)   // 4096 rows
#define NCH 32       // chunks per (b,h): NT/64

// ---- dtype hedge: inputs may be bf16 (harness-converted) or fp32 (per reference) ----
__global__ void detect_dtype(const unsigned short* __restrict__ hs, int* __restrict__ flag) {
  if (threadIdx.x == 0 && blockIdx.x == 0) {
    int cnt = 0;
    for (int i = 0; i < 2048; i += 2) {
      int e = (hs[i] >> 7) & 0xFF;
      if (e >= 141) ++cnt;
    }
    *flag = (cnt > 64) ? 1 : 0;   // 1 = fp32, 0 = bf16
  }
}

__device__ __forceinline__ float loadf(const void* p, size_t i, int isf32) {
  return isf32 ? ((const float*)p)[i] : __bfloat162float(((const bf16*)p)[i]);
}

__global__ __launch_bounds__(256) void convert_bf16(const void* __restrict__ src,
                                                    bf16* __restrict__ dst,
                                                    long n, const int* __restrict__ flag) {
  const long i0 = ((long)blockIdx.x * 256 + threadIdx.x) * 8;
  if (i0 >= n) return;
  if (*flag) {
    const float* s = (const float*)src;
    #pragma unroll
    for (int j = 0; j < 8; ++j) dst[i0 + j] = __float2bfloat16(s[i0 + j]);
  } else {
    *(short8*)(dst + i0) = *(const short8*)((const bf16*)src + i0);
  }
}

// ---- transpose + convert one matrix: dst[c][r] = bf16(src[r][c]); zero-pad cols ----
__global__ __launch_bounds__(256) void transpose_cvt(const void* __restrict__ src,
                                                     bf16* __restrict__ dst,
                                                     int src_rows, int src_cols,
                                                     const int* __restrict__ flag) {
  __shared__ bf16 tile[64][65];
  const int f = *flag;
  const int tb_r = blockIdx.y * 64, tb_c = blockIdx.x * 64;
  const int tx = threadIdx.x & 63, ty = threadIdx.x >> 6;
  #pragma unroll
  for (int i = 0; i < 64; i += 4) {
    const int cc = tb_c + tx;
    tile[i + ty][tx] = (cc < src_cols)
      ? __float2bfloat16(loadf(src, (size_t)(tb_r + i + ty) * src_cols + cc, f))
      : __float2bfloat16(0.f);
  }
  __syncthreads();
  #pragma unroll
  for (int i = 0; i < 64; i += 4)
    dst[(size_t)(tb_c + i + ty) * src_rows + tb_r + tx] = tile[tx][i + ty];
}

// ---- merged transpose of Wq/Wk/Wv/Wb into WT, z-sliced ----
__global__ __launch_bounds__(256) void transpose_qkvb(const void* __restrict__ Wq,
                                                      const void* __restrict__ Wk,
                                                      const void* __restrict__ Wv,
                                                      const void* __restrict__ Wb,
                                                      bf16* __restrict__ WT,
                                                      const int* __restrict__ flag) {
  __shared__ bf16 tile[64][65];
  const int z = blockIdx.z;
  if (z == 3 && blockIdx.x >= 2) return;   // Wb^T has only 128 padded rows
  const void* src = (z == 0) ? Wq : (z == 1) ? Wk : (z == 2) ? Wv : Wb;
  const int src_cols = (z == 3) ? 32 : 2048;
  bf16* dst = WT + (size_t)z * 2048 * 2048;
  const int f = *flag;
  const int tb_r = blockIdx.y * 64, tb_c = blockIdx.x * 64;
  const int tx = threadIdx.x & 63, ty = threadIdx.x >> 6;
  #pragma unroll
  for (int i = 0; i < 64; i += 4) {
    const int cc = tb_c + tx;
    tile[i + ty][tx] = (cc < src_cols)
      ? __float2bfloat16(loadf(src, (size_t)(tb_r + i + ty) * src_cols + cc, f))
      : __float2bfloat16(0.f);
  }
  __syncthreads();
  #pragma unroll
  for (int i = 0; i < 64; i += 4)
    dst[(size_t)(tb_c + i + ty) * 2048 + tb_r + tx] = tile[tx][i + ty];
}

// async 16B/lane global->LDS (wave-uniform LDS base + lane*16)
__device__ __forceinline__ void gload_lds16(const void* g, void* l) {
  __builtin_amdgcn_global_load_lds((__attribute__((address_space(1))) const void*)g,
                                   (__attribute__((address_space(3))) void*)l,
                                   16, 0, 0);
}

// ------------- GEMM: C = A[M][K] @ Bt[n][K]^T  (bf16 in, fp32 acc) -------------
// outflag == null: routed epilogue by global col gn = n_base + n0:
//   seg = gn>>11: 0->oq, 1->ok (both l2-normalized per 64-col head row), 2->ov, 3->ob.
// outflag != null: write outv (fp32/bf16 per *outflag), stride 2048, no norm.
__global__ __launch_bounds__(256) void gemm_bt(const bf16* __restrict__ A,
                                               const bf16* __restrict__ Bt,
                                               bf16* __restrict__ oq, bf16* __restrict__ ok2,
                                               bf16* __restrict__ ov, bf16* __restrict__ ob,
                                               void* __restrict__ outv,
                                               const int* __restrict__ outflag,
                                               int M, int K, int n_base) {
  __shared__ bf16 As[128 * 32];
  __shared__ bf16 Bs[128 * 32];
  const int tid = threadIdx.x;
  const int wave = tid >> 6, lane = tid & 63;
  const int m0 = blockIdx.y * 128, n0 = blockIdx.x * 128;
  const int wm = (wave >> 1) * 64, wn = (wave & 1) * 64;
  const int srow = lane >> 2, scol = (lane & 3) * 8;
  const int frow = lane & 15, fk = (lane >> 4) * 8;
  f32x4 acc[4][4] = {};

  for (int kb = 0; kb < K; kb += 32) {
    __syncthreads();
    #pragma unroll
    for (int j = 0; j < 2; ++j) {
      const int rbase = wave * 32 + j * 16;
      gload_lds16(A  + (size_t)(m0 + rbase + srow) * K + kb + scol, As + rbase * 32);
      gload_lds16(Bt + (size_t)(n0 + rbase + srow) * K + kb + scol, Bs + rbase * 32);
    }
    __syncthreads();
    short8 af[4], bfr[4];
    #pragma unroll
    for (int i = 0; i < 4; ++i)
      af[i] = *(const short8*)(As + (wm + i * 16 + frow) * 32 + fk);
    #pragma unroll
    for (int i = 0; i < 4; ++i)
      bfr[i] = *(const short8*)(Bs + (wn + i * 16 + frow) * 32 + fk);
    #pragma unroll
    for (int mi = 0; mi < 4; ++mi)
      #pragma unroll
      for (int ni = 0; ni < 4; ++ni)
        acc[mi][ni] = __builtin_amdgcn_mfma_f32_16x16x32_bf16(af[mi], bfr[ni], acc[mi][ni], 0, 0, 0);
  }

  // C/D layout: col = lane&15, row = (lane>>4)*4 + reg  [m89-verified]
  const int crow = (lane >> 4) * 4, ccol = lane & 15;
  const int gn0 = n_base + n0;
  if (outflag) {
    const int f = *outflag;
    #pragma unroll
    for (int mi = 0; mi < 4; ++mi)
      #pragma unroll
      for (int ni = 0; ni < 4; ++ni)
        #pragma unroll
        for (int r = 0; r < 4; ++r) {
          const size_t idx = (size_t)(m0 + wm + mi * 16 + crow + r) * 2048 + gn0 + wn + ni * 16 + ccol;
          const float val = acc[mi][ni][r];
          if (f == 1) ((float*)outv)[idx] = val;
          else        ((bf16*)outv)[idx] = __float2bfloat16(val);
        }
  } else {
    const int seg = gn0 >> 11;
    bf16* o = (seg == 0) ? oq : (seg == 1) ? ok2 : (seg == 2) ? ov : ob;
    const int stride = (seg < 3) ? 2048 : 128;
    const int cb = (gn0 & 2047) + wn;
    if (seg <= 1) {
      // fused l2norm: wave's 64-col span == one head segment; rows live in the quad
      #pragma unroll
      for (int mi = 0; mi < 4; ++mi)
        #pragma unroll
        for (int r = 0; r < 4; ++r) {
          float s = acc[mi][0][r] * acc[mi][0][r] + acc[mi][1][r] * acc[mi][1][r]
                  + acc[mi][2][r] * acc[mi][2][r] + acc[mi][3][r] * acc[mi][3][r];
          s += __shfl_xor(s, 1, 64); s += __shfl_xor(s, 2, 64);
          s += __shfl_xor(s, 4, 64); s += __shfl_xor(s, 8, 64);
          const float inv = rsqrtf(s + 1e-6f);
          #pragma unroll
          for (int ni = 0; ni < 4; ++ni) acc[mi][ni][r] *= inv;
        }
    }
    #pragma unroll
    for (int mi = 0; mi < 4; ++mi)
      #pragma unroll
      for (int ni = 0; ni < 4; ++ni)
        #pragma unroll
        for (int r = 0; r < 4; ++r)
          o[(size_t)(m0 + wm + mi * 16 + crow + r) * stride + cb + ni * 16 + ccol] =
            __float2bfloat16(acc[mi][ni][r]);
  }
}

// ======================= fused-path chunk kernels =======================

// pass 1: local scans + per-chunk matmul precomputes.
// Waves 0,1 run the 64-step delta-rule scans (w0: values=V -> U^T; w1: values=K -> G^T
// + coalesced Gneg rows). Waves 2,3 build K^T during the scan. Then all 4 waves MFMA:
// AcT = K^T*Gneg, Dc = U^T*K; U^T stored transposed-in-place into v16.
__global__ __launch_bounds__(256) void chunk_scan(const bf16* __restrict__ k16,
                                                  bf16* __restrict__ v16,
                                                  const bf16* __restrict__ betab,
                                                  const void* __restrict__ bb,
                                                  const int* __restrict__ flag,
                                                  bf16* __restrict__ Gneg,
                                                  bf16* __restrict__ AcT,
                                                  bf16* __restrict__ Dc) {
  __shared__ bf16 Ks[64 * 72];    // K rows (scan); later Dc roundtrip (flat 64)
  __shared__ bf16 Vs[64 * 72];    // V rows (scan); later AcT roundtrip (flat 64)
  __shared__ bf16 KTs[64 * 72];   // K^T rows [d][t]
  __shared__ bf16 GsT[64 * 72];   // Gneg^T rows [d][t]
  __shared__ bf16 UsT[64 * 72];   // U^T rows [v][t]
  __shared__ float Bsc[64];
  const int ch = blockIdx.x;
  const int c = ch & (NCH - 1), bh = ch >> 5;
  const int h = bh & (NH - 1), b = bh >> 5;
  const int tid = threadIdx.x, wave = tid >> 6, lane = tid & 63;
  const size_t rowb = ((size_t)b * NT + c * 64) * ND + (size_t)h * 64;
  {
    const int r0 = tid >> 3, sc = (tid & 7) * 8;
    #pragma unroll
    for (int rnd = 0; rnd < 2; ++rnd) {
      const int r = rnd * 32 + r0;
      *(short8*)(Ks + r * 72 + sc) = *(const short8*)(k16 + rowb + (size_t)r * ND + sc);
      *(short8*)(Vs + r * 72 + sc) = *(const short8*)(v16 + rowb + (size_t)r * ND + sc);
    }
  }
  if (tid < 64) {
    const float x = __bfloat162float(betab[((size_t)b * NT + c * 64 + tid) * 128 + h])
                    + loadf(bb, h, *flag);
    Bsc[tid] = 1.f / (1.f + expf(-x));
  }
  if (wave >= 2) {   // K^T fill from global rows (concurrent with staging/scan)
    const int w2 = wave - 2;
    #pragma unroll
    for (int half = 0; half < 2; ++half) {
      const int d0 = w2 * 16 + half * 32;
      short8 rA = *(const short8*)(k16 + rowb + (size_t)lane * ND + d0);
      short8 rB = *(const short8*)(k16 + rowb + (size_t)lane * ND + d0 + 8);
      #pragma unroll
      for (int j = 0; j < 8; ++j) {
        KTs[(d0 + j) * 72 + lane]     = ((const bf16*)&rA)[j];
        KTs[(d0 + 8 + j) * 72 + lane] = ((const bf16*)&rB)[j];
      }
    }
  }
  __syncthreads();
  if (wave < 2) {   // the two scans
    float S[64];
    #pragma unroll
    for (int i = 0; i < 64; ++i) S[i] = 0.f;
    const bf16* val_src = wave ? Ks : Vs;
    bf16* gout = Gneg + (size_t)ch * 4096;
    #pragma unroll 1
    for (int t = 0; t < 64; ++t) {
      uint4 ku[8];
      #pragma unroll
      for (int i = 0; i < 8; ++i) ku[i] = ((const uint4*)(Ks + t * 72))[i];  // wave-uniform
      const float val = __bfloat162float(val_src[t * 72 + lane]);
      const float bt = Bsc[t];
      float kvf[64];
      #pragma unroll
      for (int i = 0; i < 8; ++i) {
        kvf[8*i+0] = __uint_as_float(ku[i].x << 16);
        kvf[8*i+1] = __uint_as_float(ku[i].x & 0xffff0000u);
        kvf[8*i+2] = __uint_as_float(ku[i].y << 16);
        kvf[8*i+3] = __uint_as_float(ku[i].y & 0xffff0000u);
        kvf[8*i+4] = __uint_as_float(ku[i].z << 16);
        kvf[8*i+5] = __uint_as_float(ku[i].z & 0xffff0000u);
        kvf[8*i+6] = __uint_as_float(ku[i].w << 16);
        kvf[8*i+7] = __uint_as_float(ku[i].w & 0xffff0000u);
      }
      float p0 = 0, p1 = 0, p2 = 0, p3 = 0;
      #pragma unroll
      for (int i = 0; i < 16; ++i) {
        p0 += kvf[4*i+0] * S[4*i+0];
        p1 += kvf[4*i+1] * S[4*i+1];
        p2 += kvf[4*i+2] * S[4*i+2];
        p3 += kvf[4*i+3] * S[4*i+3];
      }
      const float u = bt * (val - ((p0 + p1) + (p2 + p3)));
      #pragma unroll
      for (int i = 0; i < 16; ++i) {
        S[4*i+0] += kvf[4*i+0] * u;
        S[4*i+1] += kvf[4*i+1] * u;
        S[4*i+2] += kvf[4*i+2] * u;
        S[4*i+3] += kvf[4*i+3] * u;
      }
      if (wave) {
        const bf16 gv = __float2bfloat16(-u);
        gout[t * 64 + lane] = gv;        // Gneg rows, coalesced
        GsT[lane * 72 + t] = gv;         // Gneg^T
      } else {
        UsT[lane * 72 + t] = __float2bfloat16(u);   // U^T
      }
    }
  }
  __syncthreads();
  // MFMA: AcT = K^T*Gneg (MFMA(KTs,GsT)); Dc = U^T*K (MFMA(UsT,KTs))
  const int frow = lane & 15, fk = (lane >> 4) * 8, cm = (lane >> 4) * 4;
  short8 ka0 = *(const short8*)(KTs + (16 * wave + frow) * 72 + fk);
  short8 ka1 = *(const short8*)(KTs + (16 * wave + frow) * 72 + 32 + fk);
  short8 uu0 = *(const short8*)(UsT + (16 * wave + frow) * 72 + fk);
  short8 uu1 = *(const short8*)(UsT + (16 * wave + frow) * 72 + 32 + fk);
  #pragma unroll
  for (int n = 0; n < 4; ++n) {
    f32x4 aA = {}, aD = {};
    aA = __builtin_amdgcn_mfma_f32_16x16x32_bf16(ka0, *(const short8*)(GsT + (16 * n + frow) * 72 + fk), aA, 0, 0, 0);
    aA = __builtin_amdgcn_mfma_f32_16x16x32_bf16(ka1, *(const short8*)(GsT + (16 * n + frow) * 72 + 32 + fk), aA, 0, 0, 0);
    aD = __builtin_amdgcn_mfma_f32_16x16x32_bf16(uu0, *(const short8*)(KTs + (16 * n + frow) * 72 + fk), aD, 0, 0, 0);
    aD = __builtin_amdgcn_mfma_f32_16x16x32_bf16(uu1, *(const short8*)(KTs + (16 * n + frow) * 72 + 32 + fk), aD, 0, 0, 0);
    #pragma unroll
    for (int r = 0; r < 4; ++r) {
      Vs[(16 * wave + cm + r) * 64 + 16 * n + frow] = __float2bfloat16(aA[r]);  // AcT roundtrip
      Ks[(16 * wave + cm + r) * 64 + 16 * n + frow] = __float2bfloat16(aD[r]);  // Dc roundtrip
    }
  }
  __syncthreads();
  {  // coalesced writeback: AcT, Dc, U^T (transposed-in-place into v16)
    const int r0 = tid >> 2, sc2 = (tid & 3) * 16;
    bf16* acg = AcT + (size_t)ch * 4096;
    bf16* dcg = Dc  + (size_t)ch * 4096;
    *(short8*)(acg + r0 * 64 + sc2)     = *(const short8*)(Vs + r0 * 64 + sc2);
    *(short8*)(acg + r0 * 64 + sc2 + 8) = *(const short8*)(Vs + r0 * 64 + sc2 + 8);
    *(short8*)(dcg + r0 * 64 + sc2)     = *(const short8*)(Ks + r0 * 64 + sc2);
    *(short8*)(dcg + r0 * 64 + sc2 + 8) = *(const short8*)(Ks + r0 * 64 + sc2 + 8);
    *(short8*)(v16 + rowb + (size_t)r0 * ND + sc2)     = *(const short8*)(UsT + r0 * 72 + sc2);
    *(short8*)(v16 + rowb + (size_t)r0 * ND + sc2 + 8) = *(const short8*)(UsT + r0 * 72 + sc2 + 8);
  }
}

// pass 2: minimal serial recurrence: sacc(fp32) += S_bf16 @ AcT^T + Dc, per chunk.
// B-frags and Dc values prefetched one chunk ahead; 8 MFMA + 2 barriers per chunk.
__global__ __launch_bounds__(256) void state_seq(const bf16* __restrict__ AcT,
                                                 const bf16* __restrict__ Dc,
                                                 bf16* __restrict__ Sbuf) {
  __shared__ bf16 ST[64 * 72];   // current S^T rows [v][k]
  const int bh = blockIdx.x;
  const int wave = threadIdx.x >> 6, lane = threadIdx.x & 63;
  const int frow = lane & 15, fk = (lane >> 4) * 8, cm = (lane >> 4) * 4;
  for (int i = threadIdx.x; i < 64 * 72 / 2; i += 256) ((unsigned int*)ST)[i] = 0u;
  f32x4 sacc[4] = {};
  const bf16* ac = AcT + (size_t)bh * NCH * 4096;
  const bf16* dc = Dc  + (size_t)bh * NCH * 4096;
  bf16* sb = Sbuf + (size_t)bh * NCH * 4096;
  // Sbuf[0] = 0
  #pragma unroll
  for (int n = 0; n < 4; ++n)
    #pragma unroll
    for (int r = 0; r < 4; ++r)
      sb[(16 * wave + cm + r) * 64 + 16 * n + frow] = __float2bfloat16(0.f);
  // prefetch chunk 0
  short8 bpre[4][2];
  float dpre[16];
  #pragma unroll
  for (int n = 0; n < 4; ++n) {
    bpre[n][0] = *(const short8*)(ac + (16 * n + frow) * 64 + fk);
    bpre[n][1] = *(const short8*)(ac + (16 * n + frow) * 64 + 32 + fk);
    #pragma unroll
    for (int r = 0; r < 4; ++r)
      dpre[n * 4 + r] = __bfloat162float(dc[(16 * wave + cm + r) * 64 + 16 * n + frow]);
  }
  __syncthreads();
  #pragma unroll 1
  for (int c = 0; c < NCH; ++c) {
    short8 a0 = *(const short8*)(ST + (16 * wave + frow) * 72 + fk);
    short8 a1 = *(const short8*)(ST + (16 * wave + frow) * 72 + 32 + fk);
    short8 bcur[4][2];
    float dcur[16];
    #pragma unroll
    for (int n = 0; n < 4; ++n) {
      bcur[n][0] = bpre[n][0]; bcur[n][1] = bpre[n][1];
      #pragma unroll
      for (int r = 0; r < 4; ++r) dcur[n * 4 + r] = dpre[n * 4 + r];
    }
    if (c + 1 < NCH) {   // prefetch next chunk
      const bf16* acn = ac + (size_t)(c + 1) * 4096;
      const bf16* dcn = dc + (size_t)(c + 1) * 4096;
      #pragma unroll
      for (int n = 0; n < 4; ++n) {
        bpre[n][0] = *(const short8*)(acn + (16 * n + frow) * 64 + fk);
        bpre[n][1] = *(const short8*)(acn + (16 * n + frow) * 64 + 32 + fk);
        #pragma unroll
        for (int r = 0; r < 4; ++r)
          dpre[n * 4 + r] = __bfloat162float(dcn[(16 * wave + cm + r) * 64 + 16 * n + frow]);
      }
    }
    #pragma unroll
    for (int n = 0; n < 4; ++n) {
      sacc[n] = __builtin_amdgcn_mfma_f32_16x16x32_bf16(a0, bcur[n][0], sacc[n], 0, 0, 0);
      sacc[n] = __builtin_amdgcn_mfma_f32_16x16x32_bf16(a1, bcur[n][1], sacc[n], 0, 0, 0);
      #pragma unroll
      for (int r = 0; r < 4; ++r) sacc[n][r] += dcur[n * 4 + r];
    }
    __syncthreads();   // all ST reads done
    #pragma unroll
    for (int n = 0; n < 4; ++n)
      #pragma unroll
      for (int r = 0; r < 4; ++r) {
        const bf16 sv = __float2bfloat16(sacc[n][r]);
        ST[(16 * wave + cm + r) * 72 + 16 * n + frow] = sv;
        if (c + 1 < NCH)
          sb[(size_t)(c + 1) * 4096 + (16 * wave + cm + r) * 64 + 16 * n + frow] = sv;
      }
    __syncthreads();   // ST = S_{c+1}^T
  }
}

// pass 3: chunk-parallel outputs. O = Q*S_c + tril(QK^T)*U_c, in place over q16.
// U_c^T = U^T + S^T*Gneg^T (MFMA, acc from staged U^T).
__global__ __launch_bounds__(256) void chunk_out(bf16* __restrict__ q16,
                                                 const bf16* __restrict__ k16,
                                                 const bf16* __restrict__ v16,   // U^T chunks
                                                 const bf16* __restrict__ Gneg,
                                                 const bf16* __restrict__ Sbuf) {
  __shared__ bf16 UTs[64 * 72];
  __shared__ bf16 Pt[64 * 72];
  const int ch = blockIdx.x;
  const int c = ch & (NCH - 1), bh = ch >> 5;
  const int h = bh & (NH - 1), b = bh >> 5;
  const int tid = threadIdx.x, wave = tid >> 6, lane = tid & 63;
  const int frow = lane & 15, fk = (lane >> 4) * 8, cm = (lane >> 4) * 4;
  const size_t qkb = ((size_t)b * NT + c * 64) * ND + (size_t)h * 64;
  const bf16* Sb = Sbuf + (size_t)ch * 4096;
  const bf16* Gc = Gneg + (size_t)ch * 4096;
  {  // stage U^T from v16 (coalesced)
    const int r0 = tid >> 2, sc2 = (tid & 3) * 16;
    *(short8*)(UTs + r0 * 72 + sc2)     = *(const short8*)(v16 + qkb + (size_t)r0 * ND + sc2);
    *(short8*)(UTs + r0 * 72 + sc2 + 8) = *(const short8*)(v16 + qkb + (size_t)r0 * ND + sc2 + 8);
  }
  short8 qa0 = *(const short8*)(q16 + qkb + (size_t)(16 * wave + frow) * ND + fk);
  short8 qa1 = *(const short8*)(q16 + qkb + (size_t)(16 * wave + frow) * ND + 32 + fk);
  f32x4 pacc[4];
  #pragma unroll
  for (int n = 0; n < 4; ++n) {
    f32x4 a = {};
    a = __builtin_amdgcn_mfma_f32_16x16x32_bf16(qa0, *(const short8*)(k16 + qkb + (size_t)(16 * n + frow) * ND + fk), a, 0, 0, 0);
    a = __builtin_amdgcn_mfma_f32_16x16x32_bf16(qa1, *(const short8*)(k16 + qkb + (size_t)(16 * n + frow) * ND + 32 + fk), a, 0, 0, 0);
    pacc[n] = a;
  }
  __syncthreads();   // UTs staged
  f32x4 uacc[4];
  #pragma unroll
  for (int n = 0; n < 4; ++n)
    #pragma unroll
    for (int r = 0; r < 4; ++r)
      uacc[n][r] = __bfloat162float(UTs[(16 * wave + cm + r) * 72 + 16 * n + frow]);
  #pragma unroll
  for (int n = 0; n < 4; ++n)
    #pragma unroll
    for (int r = 0; r < 4; ++r) {
      const int mg = 16 * wave + cm + r, ng = 16 * n + frow;
      Pt[mg * 72 + ng] = __float2bfloat16(ng <= mg ? pacc[n][r] : 0.f);
    }
  short8 sa0 = *(const short8*)(Sb + (16 * wave + frow) * 64 + fk);
  short8 sa1 = *(const short8*)(Sb + (16 * wave + frow) * 64 + 32 + fk);
  #pragma unroll
  for (int n = 0; n < 4; ++n) {
    uacc[n] = __builtin_amdgcn_mfma_f32_16x16x32_bf16(sa0, *(const short8*)(Gc + (16 * n + frow) * 64 + fk), uacc[n], 0, 0, 0);
    uacc[n] = __builtin_amdgcn_mfma_f32_16x16x32_bf16(sa1, *(const short8*)(Gc + (16 * n + frow) * 64 + 32 + fk), uacc[n], 0, 0, 0);
  }
  __syncthreads();   // all UTs (old) reads done
  #pragma unroll
  for (int n = 0; n < 4; ++n)
    #pragma unroll
    for (int r = 0; r < 4; ++r)
      UTs[(16 * wave + cm + r) * 72 + 16 * n + frow] = __float2bfloat16(uacc[n][r]);
  __syncthreads();   // UTs = U_c^T; Pt ready
  short8 pa0 = *(const short8*)(Pt + (16 * wave + frow) * 72 + fk);
  short8 pa1 = *(const short8*)(Pt + (16 * wave + frow) * 72 + 32 + fk);
  #pragma unroll
  for (int n = 0; n < 4; ++n) {
    f32x4 o = {};
    o = __builtin_amdgcn_mfma_f32_16x16x32_bf16(qa0, *(const short8*)(Sb + (16 * n + frow) * 64 + fk), o, 0, 0, 0);
    o = __builtin_amdgcn_mfma_f32_16x16x32_bf16(qa1, *(const short8*)(Sb + (16 * n + frow) * 64 + 32 + fk), o, 0, 0, 0);
    o = __builtin_amdgcn_mfma_f32_16x16x32_bf16(pa0, *(const short8*)(UTs + (16 * n + frow) * 72 + fk), o, 0, 0, 0);
    o = __builtin_amdgcn_mfma_f32_16x16x32_bf16(pa1, *(const short8*)(UTs + (16 * n + frow) * 72 + 32 + fk), o, 0, 0, 0);
    #pragma unroll
    for (int r = 0; r < 4; ++r)
      q16[qkb + (size_t)(16 * wave + cm + r) * ND + 16 * n + frow] = __float2bfloat16(o[r]);
  }
}

// ======================= compact-fallback chunk kernels (round-4 proven) =======================

__global__ __launch_bounds__(128) void chunk_scan_c(const bf16* __restrict__ k16,
                                                    bf16* __restrict__ v16,
                                                    const bf16* __restrict__ betab,
                                                    const void* __restrict__ bb,
                                                    const int* __restrict__ flag,
                                                    bf16* __restrict__ Gneg) {
  __shared__ bf16 Ks[64 * 64];
  __shared__ bf16 Vs[64 * 64];
  __shared__ bf16 Gs[64 * 64];
  __shared__ float Bs[64];
  const int ch = blockIdx.x;
  const int c = ch & (NCH - 1), bh = ch >> 5;
  const int h = bh & (NH - 1), b = bh >> 5;
  const int tid = threadIdx.x;
  const int wave = tid >> 6, lane = tid & 63;
  const size_t rowb = ((size_t)b * NT + c * 64) * ND + (size_t)h * 64;
  const int sr = tid >> 3, sc = (tid & 7) * 8;
  #pragma unroll
  for (int rnd = 0; rnd < 4; ++rnd) {
    const int r = rnd * 16 + sr;
    *(short8*)(Ks + r * 64 + sc) = *(const short8*)(k16 + rowb + (size_t)r * ND + sc);
    *(short8*)(Vs + r * 64 + sc) = *(const short8*)(v16 + rowb + (size_t)r * ND + sc);
  }
  if (tid < 64) {
    const float x = __bfloat162float(betab[((size_t)b * NT + c * 64 + tid) * 128 + h])
                    + loadf(bb, h, *flag);
    Bs[tid] = 1.f / (1.f + expf(-x));
  }
  __syncthreads();
  float S[64];
  #pragma unroll
  for (int i = 0; i < 64; ++i) S[i] = 0.f;
  const bf16* val_src = wave ? Ks : Vs;
  #pragma unroll 1
  for (int t = 0; t < 64; ++t) {
    uint4 ku[8];
    #pragma unroll
    for (int i = 0; i < 8; ++i) ku[i] = ((const uint4*)(Ks + t * 64))[i];
    const float val = __bfloat162float(val_src[t * 64 + lane]);
    const float bt = Bs[t];
    float kvf[64];
    #pragma unroll
    for (int i = 0; i < 8; ++i) {
      kvf[8*i+0] = __uint_as_float(ku[i].x << 16);
      kvf[8*i+1] = __uint_as_float(ku[i].x & 0xffff0000u);
      kvf[8*i+2] = __uint_as_float(ku[i].y << 16);
      kvf[8*i+3] = __uint_as_float(ku[i].y & 0xffff0000u);
      kvf[8*i+4] = __uint_as_float(ku[i].z << 16);
      kvf[8*i+5] = __uint_as_float(ku[i].z & 0xffff0000u);
      kvf[8*i+6] = __uint_as_float(ku[i].w << 16);
      kvf[8*i+7] = __uint_as_float(ku[i].w & 0xffff0000u);
    }
    float p0 = 0, p1 = 0, p2 = 0, p3 = 0;
    #pragma unroll
    for (int i = 0; i < 16; ++i) {
      p0 += kvf[4*i+0] * S[4*i+0];
      p1 += kvf[4*i+1] * S[4*i+1];
      p2 += kvf[4*i+2] * S[4*i+2];
      p3 += kvf[4*i+3] * S[4*i+3];
    }
    const float u = bt * (val - ((p0 + p1) + (p2 + p3)));
    #pragma unroll
    for (int i = 0; i < 16; ++i) {
      S[4*i+0] += kvf[4*i+0] * u;
      S[4*i+1] += kvf[4*i+1] * u;
      S[4*i+2] += kvf[4*i+2] * u;
      S[4*i+3] += kvf[4*i+3] * u;
    }
    if (wave) Gs[t * 64 + lane] = __float2bfloat16(-u);
    else      Vs[t * 64 + lane] = __float2bfloat16(u);
  }
  __syncthreads();
  bf16* gout = Gneg + (size_t)ch * 4096;
  #pragma unroll
  for (int rnd = 0; rnd < 4; ++rnd) {
    const int r = rnd * 16 + sr;
    *(short8*)(v16 + rowb + (size_t)r * ND + sc) = *(const short8*)(Vs + r * 64 + sc);
    *(short8*)(gout + r * 64 + sc)               = *(const short8*)(Gs + r * 64 + sc);
  }
}

__global__ __launch_bounds__(256) void chunk_seq_mono(bf16* q16,
                                                      const bf16* __restrict__ k16,
                                                      const bf16* __restrict__ Ul,
                                                      const bf16* __restrict__ Gneg) {
  __shared__ bf16 ST[64 * 72];
  __shared__ bf16 Ubt[64 * 72];
  __shared__ bf16 Pt[64 * 72];
  __shared__ bf16 KTl[64 * 72];
  const int bh = blockIdx.x, h = bh & (NH - 1), b = bh >> 5;
  const int wave = threadIdx.x >> 6, lane = threadIdx.x & 63;
  const int frow = lane & 15, q4 = lane >> 4, fk = q4 * 8;
  const int cm = q4 * 4;
  for (int i = threadIdx.x; i < 64 * 72 / 2; i += 256) ((unsigned int*)ST)[i] = 0u;
  __syncthreads();
  f32x4 sacc[4] = {};
  #pragma unroll 1
  for (int c = 0; c < NCH; ++c) {
    const bf16* Gc = Gneg + ((size_t)bh * NCH + c) * 4096;
    const size_t qkb = ((size_t)b * NT + c * 64) * ND + (size_t)h * 64;
    {
      short8 r0 = *(const short8*)(k16 + qkb + (size_t)lane * ND + 16 * wave);
      short8 r1 = *(const short8*)(k16 + qkb + (size_t)lane * ND + 16 * wave + 8);
      #pragma unroll
      for (int j = 0; j < 8; ++j) {
        KTl[(16 * wave + j) * 72 + lane]     = ((const bf16*)&r0)[j];
        KTl[(16 * wave + 8 + j) * 72 + lane] = ((const bf16*)&r1)[j];
      }
    }
    short8 ga0 = *(const short8*)(Gc + (16 * wave + frow) * 64 + fk);
    short8 ga1 = *(const short8*)(Gc + (16 * wave + frow) * 64 + 32 + fk);
    #pragma unroll
    for (int n = 0; n < 4; ++n) {
      f32x4 acc;
      #pragma unroll
      for (int r = 0; r < 4; ++r)
        acc[r] = __bfloat162float(Ul[qkb + (size_t)(16 * wave + cm + r) * ND + 16 * n + frow]);
      acc = __builtin_amdgcn_mfma_f32_16x16x32_bf16(ga0, *(const short8*)(ST + (16 * n + frow) * 72 + fk), acc, 0, 0, 0);
      acc = __builtin_amdgcn_mfma_f32_16x16x32_bf16(ga1, *(const short8*)(ST + (16 * n + frow) * 72 + 32 + fk), acc, 0, 0, 0);
      #pragma unroll
      for (int r = 0; r < 4; ++r)
        Ubt[(16 * n + frow) * 72 + 16 * wave + cm + r] = __float2bfloat16(acc[r]);
    }
    __syncthreads();
    short8 qa0 = *(const short8*)(q16 + qkb + (size_t)(16 * wave + frow) * ND + fk);
    short8 qa1 = *(const short8*)(q16 + qkb + (size_t)(16 * wave + frow) * ND + 32 + fk);
    #pragma unroll
    for (int n = 0; n < 4; ++n) {
      f32x4 acc = {};
      acc = __builtin_amdgcn_mfma_f32_16x16x32_bf16(qa0, *(const short8*)(k16 + qkb + (size_t)(16 * n + frow) * ND + fk), acc, 0, 0, 0);
      acc = __builtin_amdgcn_mfma_f32_16x16x32_bf16(qa1, *(const short8*)(k16 + qkb + (size_t)(16 * n + frow) * ND + 32 + fk), acc, 0, 0, 0);
      #pragma unroll
      for (int r = 0; r < 4; ++r) {
        const int mg = 16 * wave + cm + r, ng = 16 * n + frow;
        Pt[mg * 72 + ng] = __float2bfloat16(ng <= mg ? acc[r] : 0.f);
      }
    }
    __syncthreads();
    short8 pa0 = *(const short8*)(Pt + (16 * wave + frow) * 72 + fk);
    short8 pa1 = *(const short8*)(Pt + (16 * wave + frow) * 72 + 32 + fk);
    #pragma unroll
    for (int n = 0; n < 4; ++n) {
      f32x4 acc = {};
      acc = __builtin_amdgcn_mfma_f32_16x16x32_bf16(qa0, *(const short8*)(ST + (16 * n + frow) * 72 + fk), acc, 0, 0, 0);
      acc = __builtin_amdgcn_mfma_f32_16x16x32_bf16(qa1, *(const short8*)(ST + (16 * n + frow) * 72 + 32 + fk), acc, 0, 0, 0);
      acc = __builtin_amdgcn_mfma_f32_16x16x32_bf16(pa0, *(const short8*)(Ubt + (16 * n + frow) * 72 + fk), acc, 0, 0, 0);
      acc = __builtin_amdgcn_mfma_f32_16x16x32_bf16(pa1, *(const short8*)(Ubt + (16 * n + frow) * 72 + 32 + fk), acc, 0, 0, 0);
      #pragma unroll
      for (int r = 0; r < 4; ++r)
        q16[qkb + (size_t)(16 * wave + cm + r) * ND + 16 * n + frow] = __float2bfloat16(acc[r]);
    }
    __syncthreads();
    short8 ua0 = *(const short8*)(Ubt + (16 * wave + frow) * 72 + fk);
    short8 ua1 = *(const short8*)(Ubt + (16 * wave + frow) * 72 + 32 + fk);
    #pragma unroll
    for (int n = 0; n < 4; ++n) {
      sacc[n] = __builtin_amdgcn_mfma_f32_16x16x32_bf16(ua0, *(const short8*)(KTl + (16 * n + frow) * 72 + fk), sacc[n], 0, 0, 0);
      sacc[n] = __builtin_amdgcn_mfma_f32_16x16x32_bf16(ua1, *(const short8*)(KTl + (16 * n + frow) * 72 + 32 + fk), sacc[n], 0, 0, 0);
      #pragma unroll
      for (int r = 0; r < 4; ++r)
        ST[(16 * wave + cm + r) * 72 + 16 * n + frow] = __float2bfloat16(sacc[n][r]);
    }
    __syncthreads();
  }
}

extern "C" void kernel_launch(void* const* d_in, const int* in_sizes, int n_in,
                              void* d_out, int out_size, void* d_ws, size_t ws_size,
                              hipStream_t stream) {
  const void* hs = d_in[0];
  const void* Wq = d_in[1];
  const void* Wk = d_in[2];
  const void* Wv = d_in[3];
  const void* Wb = d_in[4];
  const void* bb = d_in[5];
  const void* Wo = d_in[6];

  char* ws = (char*)d_ws;
  size_t off = 0;
  auto alloc = [&](size_t bytes) {
    void* p = ws + off;
    off += (bytes + 255) & ~(size_t)255;
    return p;
  };
  const size_t szW = (size_t)6272 * 2048 * 2;   // 24.5 MiB (Wqkvb^T)
  const size_t szM = (size_t)NM * ND * 2;       // 16 MiB
  const size_t szB = (size_t)NM * 128 * 2;      // 1 MiB (beta logits, 128-padded)
  const size_t need_fused = 512 + szW + 4 * szM + szB + 2 * szM;   // ~122.8 MB

  if (ws_size >= need_fused) {
    // ---- fused path ----
    int*  flag  = (int*) alloc(256);
    bf16* WT    = (bf16*)alloc(szW);
    bf16* hs16  = (bf16*)alloc(szM);   // -> Sbuf after fused GEMM
    bf16* q16   = (bf16*)alloc(szM);   // O in place
    bf16* k16   = (bf16*)alloc(szM);
    bf16* v16   = (bf16*)alloc(szM);   // U^T (transposed-in-place)
    bf16* betab = (bf16*)alloc(szB);
    bf16* AcT   = (bf16*)alloc(szM);   // K^T*Gneg per chunk
    bf16* Dc    = (bf16*)alloc(szM);   // U^T*K per chunk
    bf16* Gneg  = WT;                                    // WT[0,16MiB) dead after fused GEMM
    bf16* WoT   = WT + (size_t)8 * 1024 * 1024;          // WT[16,24MiB)
    bf16* Sbuf  = hs16;

    detect_dtype<<<1, 64, 0, stream>>>((const unsigned short*)hs, flag);
    convert_bf16<<<(NM * ND) / (256 * 8), 256, 0, stream>>>(hs, hs16, (long)NM * ND, flag);

    transpose_qkvb<<<dim3(32, 32, 4), 256, 0, stream>>>(Wq, Wk, Wv, Wb, WT, flag);
    gemm_bt<<<dim3(49, 32), 256, 0, stream>>>(hs16, WT, q16, k16, v16, betab,
                                              nullptr, nullptr, NM, ND, 0);

    chunk_scan<<<NB * NH * NCH, 256, 0, stream>>>(k16, v16, betab, bb, flag, Gneg, AcT, Dc);
    state_seq<<<NB * NH, 256, 0, stream>>>(AcT, Dc, Sbuf);
    chunk_out<<<NB * NH * NCH, 256, 0, stream>>>(q16, k16, v16, Gneg, Sbuf);

    transpose_cvt<<<dim3(32, 32), 256, 0, stream>>>(Wo, WoT, 2048, 2048, flag);
    gemm_bt<<<dim3(16, 32), 256, 0, stream>>>(q16, WoT, nullptr, nullptr, nullptr, nullptr,
                                              d_out, flag, NM, ND, 0);
  } else {
    // ---- compact fallback (proven ~73 MB footprint) ----
    int*  flag  = (int*) alloc(256);
    bf16* Wt    = (bf16*)alloc((size_t)2048 * 2048 * 2);
    bf16* hs16  = (bf16*)alloc(szM);   // -> Gneg
    bf16* q16   = (bf16*)alloc(szM);
    bf16* k16   = (bf16*)alloc(szM);
    bf16* v16   = (bf16*)alloc(szM);
    bf16* betab = (bf16*)alloc(szB);
    bf16* Gneg  = hs16;

    detect_dtype<<<1, 64, 0, stream>>>((const unsigned short*)hs, flag);
    convert_bf16<<<(NM * ND) / (256 * 8), 256, 0, stream>>>(hs, hs16, (long)NM * ND, flag);

    transpose_cvt<<<dim3(32, 32), 256, 0, stream>>>(Wq, Wt, 2048, 2048, flag);
    gemm_bt<<<dim3(16, 32), 256, 0, stream>>>(hs16, Wt, q16, k16, v16, betab, nullptr, nullptr, NM, ND, 0);
    transpose_cvt<<<dim3(32, 32), 256, 0, stream>>>(Wk, Wt, 2048, 2048, flag);
    gemm_bt<<<dim3(16, 32), 256, 0, stream>>>(hs16, Wt, q16, k16, v16, betab, nullptr, nullptr, NM, ND, 2048);
    transpose_cvt<<<dim3(32, 32), 256, 0, stream>>>(Wv, Wt, 2048, 2048, flag);
    gemm_bt<<<dim3(16, 32), 256, 0, stream>>>(hs16, Wt, q16, k16, v16, betab, nullptr, nullptr, NM, ND, 4096);
    transpose_cvt<<<dim3(2, 32),  256, 0, stream>>>(Wb, Wt, 2048, 32, flag);
    gemm_bt<<<dim3(1, 32), 256, 0, stream>>>(hs16, Wt, q16, k16, v16, betab, nullptr, nullptr, NM, ND, 6144);

    chunk_scan_c<<<NB * NH * NCH, 128, 0, stream>>>(k16, v16, betab, bb, flag, Gneg);
    chunk_seq_mono<<<NB * NH, 256, 0, stream>>>(q16, k16, v16, Gneg);

    transpose_cvt<<<dim3(32, 32), 256, 0, stream>>>(Wo, Wt, 2048, 2048, flag);
    gemm_bt<<<dim3(16, 32), 256, 0, stream>>>(q16, Wt, nullptr, nullptr, nullptr, nullptr,
                                              d_out, flag, NM, ND, 0);
  }
}